// Round 5
// baseline (1512.077 us; speedup 1.0000x reference)
//
#include <hip/hip_runtime.h>
#include <stdint.h>
#include <stddef.h>

typedef unsigned short u16;
typedef __bf16 bf16x8 __attribute__((ext_vector_type(8)));
typedef float f32x4 __attribute__((ext_vector_type(4)));

#define DEV __device__ __forceinline__

DEV float bf2f(u16 u){ union{uint32_t i; float f;} c; c.i=(uint32_t)u<<16; return c.f; }
DEV u16 f2bf(float f){ union{float f; uint32_t i;} c; c.f=f; uint32_t x=c.i;
  uint32_t r = x + 0x7FFFu + ((x>>16)&1u); return (u16)(r>>16); }
// monotone float->uint map (handles negatives)
DEV uint32_t fmap(float f){ union{float f; uint32_t u;} c; c.f=f;
  return (c.u & 0x80000000u) ? ~c.u : (c.u | 0x80000000u); }
DEV float funmap(uint32_t u){ union{uint32_t u; float f;} c;
  c.u = (u & 0x80000000u) ? (u & 0x7FFFFFFFu) : ~u; return c.f; }

// split fp32 -> (hi, lo) bf16 pair: x ~= hi + lo, rel err ~3e-6
DEV void split2(float x, u16& h, u16& l){
  h = f2bf(x);
  l = f2bf(x - bf2f(h));
}

// ---- block reductions (256 threads = 4 waves) ----
DEV float bredsum(float v, float* buf, int tid){
  #pragma unroll
  for(int o=32;o;o>>=1) v += __shfl_down(v,o);
  __syncthreads();
  if((tid&63)==0) buf[tid>>6]=v;
  __syncthreads();
  return buf[0]+buf[1]+buf[2]+buf[3];
}
DEV float bredmax(float v, float* buf, int tid){
  #pragma unroll
  for(int o=32;o;o>>=1) v = fmaxf(v, __shfl_down(v,o));
  __syncthreads();
  if((tid&63)==0) buf[tid>>6]=v;
  __syncthreads();
  return fmaxf(fmaxf(buf[0],buf[1]),fmaxf(buf[2],buf[3]));
}
DEV int bredsumi(int v, int* buf, int tid){
  #pragma unroll
  for(int o=32;o;o>>=1) v += __shfl_down(v,o);
  __syncthreads();
  if((tid&63)==0) buf[tid>>6]=v;
  __syncthreads();
  return buf[0]+buf[1]+buf[2]+buf[3];
}

// ============================================================================
// Split-bf16 GEMM: C = act(scale * (Ah+Al)(Bh+Bl)^T + bias), fp32-class accuracy
// via 3 MFMAs per step (hh + hl + lh). 128x128 tile, BK=32, 4 waves x 64x64.
// M,N multiples of 128; K multiple of 32. bias fp32.
// Outputs: (outh,outl) split-bf16 pair for chaining; outf fp32.
// ============================================================================
template<bool RELU>
__global__ __launch_bounds__(256)
void gemm3(const u16* __restrict__ Ah, const u16* __restrict__ Al, int lda,
           const u16* __restrict__ Bh, const u16* __restrict__ Bl, int ldb,
           const float* __restrict__ bias, float scale,
           u16* __restrict__ outh, u16* __restrict__ outl,
           float* __restrict__ outf,
           int K, int ldc)
{
  __shared__ __align__(16) u16 AsH[128*32];
  __shared__ __align__(16) u16 AsL[128*32];
  __shared__ __align__(16) u16 BsH[128*32];
  __shared__ __align__(16) u16 BsL[128*32];
  const int tid  = threadIdx.x;
  const int lane = tid & 63;
  const int wave = tid >> 6;
  const int m0 = blockIdx.y * 128;
  const int n0 = blockIdx.x * 128;
  const int wm = (wave>>1)*64, wn = (wave&1)*64;
  const int ml = lane & 15, quad = lane >> 4;

  f32x4 acc[4][4];
  #pragma unroll
  for(int i=0;i<4;i++)
    #pragma unroll
    for(int j=0;j<4;j++) acc[i][j] = (f32x4){0.f,0.f,0.f,0.f};

  for(int k0=0;k0<K;k0+=32){
    uint4 rah[2], ral[2], rbh[2], rbl[2];
    #pragma unroll
    for(int i=0;i<2;i++){
      const int c = i*256 + tid;          // chunk: row = c>>2, 8-col group = c&3
      const size_t ao = (size_t)(m0 + (c>>2))*lda + k0 + (c&3)*8;
      const size_t bo = (size_t)(n0 + (c>>2))*ldb + k0 + (c&3)*8;
      rah[i] = *(const uint4*)(Ah + ao);
      ral[i] = *(const uint4*)(Al + ao);
      rbh[i] = *(const uint4*)(Bh + bo);
      rbl[i] = *(const uint4*)(Bl + bo);
    }
    __syncthreads();                      // protect LDS from previous iter reads
    #pragma unroll
    for(int i=0;i<2;i++){
      const int c = i*256 + tid;
      *(uint4*)&AsH[c*8] = rah[i];
      *(uint4*)&AsL[c*8] = ral[i];
      *(uint4*)&BsH[c*8] = rbh[i];
      *(uint4*)&BsL[c*8] = rbl[i];
    }
    __syncthreads();
    bf16x8 afh[4], afl[4], bfh[4], bfl[4];
    #pragma unroll
    for(int mi=0;mi<4;mi++){
      const int o = (wm+mi*16+ml)*32 + quad*8;
      afh[mi] = *(const bf16x8*)&AsH[o];
      afl[mi] = *(const bf16x8*)&AsL[o];
    }
    #pragma unroll
    for(int ni=0;ni<4;ni++){
      const int o = (wn+ni*16+ml)*32 + quad*8;
      bfh[ni] = *(const bf16x8*)&BsH[o];
      bfl[ni] = *(const bf16x8*)&BsL[o];
    }
    #pragma unroll
    for(int mi=0;mi<4;mi++)
      #pragma unroll
      for(int ni=0;ni<4;ni++){
        acc[mi][ni] = __builtin_amdgcn_mfma_f32_16x16x32_bf16(afh[mi], bfh[ni], acc[mi][ni], 0,0,0);
        acc[mi][ni] = __builtin_amdgcn_mfma_f32_16x16x32_bf16(afh[mi], bfl[ni], acc[mi][ni], 0,0,0);
        acc[mi][ni] = __builtin_amdgcn_mfma_f32_16x16x32_bf16(afl[mi], bfh[ni], acc[mi][ni], 0,0,0);
      }
  }

  // C/D layout: col = lane&15, row = quad*4 + reg  (m89-verified)
  #pragma unroll
  for(int mi=0;mi<4;mi++){
    const int rbase = m0 + wm + mi*16 + quad*4;
    #pragma unroll
    for(int ni=0;ni<4;ni++){
      const int col = n0 + wn + ni*16 + ml;
      const float bv = bias ? bias[col] : 0.f;
      #pragma unroll
      for(int r=0;r<4;r++){
        float v = acc[mi][ni][r]*scale + bv;
        if(RELU) v = fmaxf(v, 0.f);
        const size_t idx = (size_t)(rbase + r)*ldc + col;
        if(outh){
          u16 h, l; split2(v, h, l);
          outh[idx] = h;
          if(outl) outl[idx] = l;
        }
        if(outf) outf[idx] = v;
      }
    }
  }
}

// ============================================================================
// fp32 transpose + bf16-split: outh/outl[C][R] = split(in[R][C]^T)
// ============================================================================
__global__ __launch_bounds__(256)
void transpose_split(const float* __restrict__ in, u16* __restrict__ outh,
                     u16* __restrict__ outl, int R, int C)
{
  __shared__ float tile[32][33];
  const int tx = threadIdx.x & 31, ty = threadIdx.x >> 5;
  const int bx = blockIdx.x*32, by = blockIdx.y*32;
  #pragma unroll
  for(int i=0;i<32;i+=8)
    tile[ty+i][tx] = in[(size_t)(by+ty+i)*C + bx + tx];
  __syncthreads();
  #pragma unroll
  for(int i=0;i<32;i+=8){
    const float v = tile[tx][ty+i];
    u16 h, l; split2(v, h, l);
    const size_t o = (size_t)(bx+ty+i)*R + by + tx;
    outh[o] = h; outl[o] = l;
  }
}

// ============================================================================
// LayerNorm over D=1024 (fp32 in), one block per row -> split-bf16 out.
// ============================================================================
__global__ __launch_bounds__(256)
void layernorm_rows(const float* __restrict__ in, const float* __restrict__ g,
                    const float* __restrict__ bb, u16* __restrict__ outh,
                    u16* __restrict__ outl, int ostride)
{
  __shared__ float buf[4];
  const int row = blockIdx.x, tid = threadIdx.x;
  const float4 xv = ((const float4*)(in + (size_t)row*1024))[tid];
  float s  = bredsum(xv.x+xv.y+xv.z+xv.w, buf, tid);
  float s2 = bredsum(xv.x*xv.x+xv.y*xv.y+xv.z*xv.z+xv.w*xv.w, buf, tid);
  const float mean = s * (1.f/1024.f);
  const float var  = s2 * (1.f/1024.f) - mean*mean;
  const float rs   = 1.f / sqrtf(var + 1e-5f);
  const float4 gv = ((const float4*)g)[tid];
  const float4 bv = ((const float4*)bb)[tid];
  float o0 = (xv.x-mean)*rs*gv.x + bv.x;
  float o1 = (xv.y-mean)*rs*gv.y + bv.y;
  float o2 = (xv.z-mean)*rs*gv.z + bv.z;
  float o3 = (xv.w-mean)*rs*gv.w + bv.w;
  ushort4 oh, ol;
  split2(o0, oh.x, ol.x); split2(o1, oh.y, ol.y);
  split2(o2, oh.z, ol.z); split2(o3, oh.w, ol.w);
  ((ushort4*)(outh + (size_t)row*ostride))[tid] = oh;
  ((ushort4*)(outl + (size_t)row*ostride))[tid] = ol;
}

// edges = LN(mu + exp(logsigma)*noise) -> split-bf16 into cat[:, :1024] (stride 2048)
__global__ __launch_bounds__(256)
void edges_ln(const float* __restrict__ noise, const float* __restrict__ mu,
              const float* __restrict__ lsig, const float* __restrict__ g,
              const float* __restrict__ bb, u16* __restrict__ outh,
              u16* __restrict__ outl, int ostride)
{
  __shared__ float buf[4];
  const int row = blockIdx.x, tid = threadIdx.x;
  const float4 nv  = ((const float4*)(noise + (size_t)row*1024))[tid];
  const float4 muv = ((const float4*)mu)[tid];
  const float4 lsv = ((const float4*)lsig)[tid];
  float v0 = muv.x + expf(lsv.x)*nv.x;
  float v1 = muv.y + expf(lsv.y)*nv.y;
  float v2 = muv.z + expf(lsv.z)*nv.z;
  float v3 = muv.w + expf(lsv.w)*nv.w;
  float s  = bredsum(v0+v1+v2+v3, buf, tid);
  float s2 = bredsum(v0*v0+v1*v1+v2*v2+v3*v3, buf, tid);
  const float mean = s * (1.f/1024.f);
  const float var  = s2 * (1.f/1024.f) - mean*mean;
  const float rs   = 1.f / sqrtf(var + 1e-5f);
  const float4 gv = ((const float4*)g)[tid];
  const float4 bv = ((const float4*)bb)[tid];
  float o0 = (v0-mean)*rs*gv.x + bv.x;
  float o1 = (v1-mean)*rs*gv.y + bv.y;
  float o2 = (v2-mean)*rs*gv.z + bv.z;
  float o3 = (v3-mean)*rs*gv.w + bv.w;
  ushort4 oh, ol;
  split2(o0, oh.x, ol.x); split2(o1, oh.y, ol.y);
  split2(o2, oh.z, ol.z); split2(o3, oh.w, ol.w);
  ((ushort4*)(outh + (size_t)row*ostride))[tid] = oh;
  ((ushort4*)(outl + (size_t)row*ostride))[tid] = ol;
}

// ============================================================================
// softmax over 8192 + eps + renorm + top-k_n selection. One block per edge row.
// Emits exactly k (idx, weight) pairs; tie-break = lowest index (JAX top_k).
// LDS padded (+1 word per 32) to break bank conflicts in the counting loops.
// ============================================================================
#define USI(i) ((i) + ((i)>>5))
__global__ __launch_bounds__(256)
void softmax_topk_a(const float* __restrict__ dots, const int* __restrict__ knp,
                    int* __restrict__ tidx, float* __restrict__ tw)
{
  const int NC = 8192;
  __shared__ uint32_t us[8192 + 256];
  __shared__ float fbuf[4];
  __shared__ int ibuf[4];
  __shared__ int scan[256];
  __shared__ int slot_ctr;
  const int row = blockIdx.x, tid = threadIdx.x;
  const float* x = dots + (size_t)row * NC;

  float mx = -3.4e38f;
  for(int i=tid;i<NC;i+=256){ float f = x[i]; us[USI(i)] = fmap(f); mx = fmaxf(mx, f); }
  mx = bredmax(mx, fbuf, tid);

  float se = 0.f;
  for(int i=tid;i<NC;i+=256) se += expf(funmap(us[USI(i)]) - mx);
  se = bredsum(se, fbuf, tid);

  float ts = 0.f;   // actual sum of (softmax + eps), matching the reference renorm
  for(int i=tid;i<NC;i+=256) ts += expf(funmap(us[USI(i)]) - mx)/se + 1e-8f;
  const float T = bredsum(ts, fbuf, tid);

  const int k = knp[0];
  // binary search for k-th largest mapped value
  uint32_t lo = 0u, hi = 0xFFFFFFFFu;
  const int base = tid*32;   // contiguous chunk per thread (index-order ties)
  while(lo < hi){
    const uint32_t mid = lo + ((hi - lo) >> 1) + 1u;
    int c = 0;
    #pragma unroll 8
    for(int j=0;j<32;j++) c += (us[USI(base+j)] >= mid);
    c = bredsumi(c, ibuf, tid);
    if(c >= k) lo = mid; else hi = mid - 1u;
  }
  const uint32_t uth = lo;

  int gt = 0, eq = 0;
  #pragma unroll 8
  for(int j=0;j<32;j++){ uint32_t u = us[USI(base+j)]; gt += (u>uth); eq += (u==uth); }
  const int c1 = bredsumi(gt, ibuf, tid);
  __syncthreads();
  scan[tid] = eq;
  __syncthreads();
  #pragma unroll
  for(int o=1;o<256;o<<=1){
    int t = (tid>=o) ? scan[tid-o] : 0;
    __syncthreads();
    scan[tid] += t;
    __syncthreads();
  }
  int eq_rank = scan[tid] - eq;          // equals before my chunk
  const int budget = k - c1;
  if(tid==0) slot_ctr = 0;
  __syncthreads();

  for(int j=0;j<32;j++){
    const int i = base + j;
    const uint32_t u = us[USI(i)];
    bool sel = (u > uth);
    if(u == uth){ sel = (eq_rank < budget); eq_rank++; }
    if(sel){
      const int s = atomicAdd(&slot_ctr, 1);
      const float f = funmap(u);
      const float w = (expf(f - mx)/se + 1e-8f) / T;
      if(s < 128){
        tidx[row*128 + s] = i;
        tw  [row*128 + s] = w;
      }
    }
  }
}

// updates[row] = sum_j w_j * v[idx_j] (fp32) ; split-bf16 into cat[:, 1024:2048]
__global__ __launch_bounds__(256)
void gather_updates(const int* __restrict__ tidx, const float* __restrict__ tw,
                    const int* __restrict__ knp, const float* __restrict__ v,
                    u16* __restrict__ cath, u16* __restrict__ catl)
{
  __shared__ int   idx_s[128];
  __shared__ float w_s[128];
  const int row = blockIdx.x, tid = threadIdx.x;
  const int kk = knp[0];
  if(tid < 128){
    idx_s[tid] = (tid < kk) ? (tidx[row*128+tid] & 8191) : 0;
    w_s[tid]   = (tid < kk) ? tw[row*128+tid] : 0.f;
  }
  __syncthreads();
  const int c = tid*4;
  float a0=0,a1=0,a2=0,a3=0;
  for(int j=0;j<kk && j<128;j++){
    const float4 vv = *(const float4*)&v[(size_t)idx_s[j]*1024 + c];
    const float w = w_s[j];
    a0 += w*vv.x; a1 += w*vv.y; a2 += w*vv.z; a3 += w*vv.w;
  }
  ushort4 oh, ol;
  split2(a0, oh.x, ol.x); split2(a1, oh.y, ol.y);
  split2(a2, oh.z, ol.z); split2(a3, oh.w, ol.w);
  ((ushort4*)(cath + (size_t)row*2048 + 1024))[tid] = oh;
  ((ushort4*)(catl + (size_t)row*2048 + 1024))[tid] = ol;
}

// ============================================================================
// H: softmax over 512 per row, keep top-k_e entries, zeros elsewhere. fp32 out.
// ============================================================================
__global__ __launch_bounds__(256)
void softmax_topk_h(const float* __restrict__ dv, const int* __restrict__ kep,
                    float* __restrict__ H)
{
  __shared__ float fbuf[4];
  __shared__ int ibuf[4];
  __shared__ int scan[256];
  const int row = blockIdx.x, tid = threadIdx.x;
  const float2 fv = ((const float2*)(dv + (size_t)row*512))[tid];
  const float f0 = fv.x, f1 = fv.y;
  const float mx = bredmax(fmaxf(f0,f1), fbuf, tid);
  const float e0 = expf(f0-mx), e1 = expf(f1-mx);
  const float se = bredsum(e0+e1, fbuf, tid);
  const float p0 = e0/se, p1 = e1/se;
  const uint32_t u0 = fmap(f0), u1 = fmap(f1);

  const int k = kep[0];
  uint32_t lo = 0u, hi = 0xFFFFFFFFu;
  while(lo < hi){
    const uint32_t mid = lo + ((hi - lo) >> 1) + 1u;
    int c = (u0 >= mid) + (u1 >= mid);
    c = bredsumi(c, ibuf, tid);
    if(c >= k) lo = mid; else hi = mid - 1u;
  }
  const uint32_t uth = lo;
  const int gt = (u0>uth) + (u1>uth);
  const int eq = (u0==uth) + (u1==uth);
  const int c1 = bredsumi(gt, ibuf, tid);
  __syncthreads();
  scan[tid] = eq;
  __syncthreads();
  #pragma unroll
  for(int o=1;o<256;o<<=1){
    int t = (tid>=o) ? scan[tid-o] : 0;
    __syncthreads();
    scan[tid] += t;
    __syncthreads();
  }
  const int eq_before = scan[tid] - eq;
  const int budget = k - c1;
  const bool s0 = (u0>uth) || ((u0==uth) && (eq_before < budget));
  const bool s1 = (u1>uth) || ((u1==uth) && (eq_before + (u0==uth?1:0) < budget));
  float2 o;
  o.x = s0 ? p0 : 0.f;
  o.y = s1 ? p1 : 0.f;
  ((float2*)(H + (size_t)row*512))[tid] = o;
}

// ============================================================================
extern "C" void kernel_launch(void* const* d_in, const int* in_sizes, int n_in,
                              void* d_out, int out_size, void* d_ws, size_t ws_size,
                              hipStream_t stream)
{
  // Inputs fp32; outputs fp32 (reference output dtype = float32).
  const float* inputs = (const float*)d_in[0];
  const float* noise  = (const float*)d_in[1];
  const float* emu    = (const float*)d_in[2];
  const float* elsig  = (const float*)d_in[3];
  const float* Wq = (const float*)d_in[4];  const float* bq = (const float*)d_in[5];
  const float* Wk = (const float*)d_in[6];  const float* bk = (const float*)d_in[7];
  const float* Wv = (const float*)d_in[8];  const float* bv = (const float*)d_in[9];
  const float* W1 = (const float*)d_in[10]; const float* b1 = (const float*)d_in[11];
  const float* W2 = (const float*)d_in[12]; const float* b2 = (const float*)d_in[13];
  const float* g_in = (const float*)d_in[14]; const float* b_in = (const float*)d_in[15];
  const float* g_e  = (const float*)d_in[16]; const float* b_e  = (const float*)d_in[17];
  const int* knp = (const int*)d_in[18];
  const int* kep = (const int*)d_in[19];

  float* out = (float*)d_out;
  float* out_edges = out;                             // 512*1024
  float* out_H     = out + 512*1024;                  // 8192*512
  float* out_dots  = out + 512*1024 + 8192*512;       // 512*8192

  // ---- workspace: stream-ordered reuse, peak ~117 MB ----
  char* p = (char*)d_ws;
  const size_t MB = 1024ull*1024;
  // Region A [0,32MB): x split (live until q2 GEMM done)
  u16* xh = (u16*)(p + 0*MB);
  u16* xl = (u16*)(p + 16*MB);
  // Region B [32,64MB): k split -> (after dots GEMM) vf fp32 -> (after gather) q2 split
  u16*   kh  = (u16*)(p + 32*MB);
  u16*   kl  = (u16*)(p + 48*MB);
  float* vf  = (float*)(p + 32*MB);
  u16*   q2h = (u16*)(p + 32*MB);
  u16*   q2l = (u16*)(p + 48*MB);
  // Region D [64,80MB): dotsf (dots_v only; dots itself goes straight to d_out)
  float* dotsf = (float*)(p + 64*MB);
  // Weights [80,104MB)
  u16* WqTh = (u16*)(p + 80*MB);  u16* WqTl = (u16*)(p + 82*MB);
  u16* WkTh = (u16*)(p + 84*MB);  u16* WkTl = (u16*)(p + 86*MB);
  u16* WvTh = (u16*)(p + 88*MB);  u16* WvTl = (u16*)(p + 90*MB);
  u16* W2Th = (u16*)(p + 92*MB);  u16* W2Tl = (u16*)(p + 94*MB);
  u16* W1Th = (u16*)(p + 96*MB);  u16* W1Tl = (u16*)(p + 100*MB);
  // cat + small [104,117MB)
  u16* cath = (u16*)(p + 104*MB); u16* catl = (u16*)(p + 106*MB);
  u16* qmh  = (u16*)(p + 108*MB); u16* qml  = (u16*)(p + 109*MB);
  u16* h1h  = (u16*)(p + 110*MB); u16* h1l  = (u16*)(p + 111*MB);
  u16* eoh  = (u16*)(p + 112*MB); u16* eol  = (u16*)(p + 113*MB);
  u16* k2h  = (u16*)(p + 114*MB); u16* k2l  = (u16*)(p + 115*MB);
  int*   tidx = (int*)  (p + 116*MB);           // 256KB
  float* tw   = (float*)(p + 116*MB + 256*1024);

  hipMemsetAsync(tidx, 0, 512ull*128*4, stream);
  hipMemsetAsync(tw,   0, 512ull*128*4, stream);

  // weight transposes + bf16 split (gemm wants Bt[n][k])
  transpose_split<<<dim3(32,32),256,0,stream>>>(Wq, WqTh, WqTl, 1024, 1024);
  transpose_split<<<dim3(32,32),256,0,stream>>>(Wk, WkTh, WkTl, 1024, 1024);
  transpose_split<<<dim3(32,32),256,0,stream>>>(Wv, WvTh, WvTl, 1024, 1024);
  transpose_split<<<dim3(32,32),256,0,stream>>>(W2, W2Th, W2Tl, 1024, 1024);
  transpose_split<<<dim3(32,64),256,0,stream>>>(W1, W1Th, W1Tl, 2048, 1024);

  layernorm_rows<<<8192,256,0,stream>>>(inputs, g_in, b_in, xh, xl, 1024);
  edges_ln<<<512,256,0,stream>>>(noise, emu, elsig, g_e, b_e, cath, catl, 2048);

  // k = relu(x@Wk+bk)  (Region B as k)
  gemm3<true ><<<dim3(8,64),256,0,stream>>>(xh,xl,1024, WkTh,WkTl,1024, bk, 1.f,
                                            kh,kl, nullptr, 1024,1024);
  // q = relu(edges_norm@Wq+bq)
  gemm3<true ><<<dim3(8,4),256,0,stream>>>(cath,catl,2048, WqTh,WqTl,1024, bq, 1.f,
                                           qmh,qml, nullptr, 1024,1024);
  // dots = q@k^T / 32 -> fp32 straight into d_out
  gemm3<false><<<dim3(64,4),256,0,stream>>>(qmh,qml,1024, kh,kl,1024, nullptr, 0.03125f,
                                            nullptr,nullptr, out_dots, 1024,8192);
  softmax_topk_a<<<512,256,0,stream>>>(out_dots, knp, tidx, tw);
  // v = relu(x@Wv+bv) -> Region B (k dead after dots GEMM)
  gemm3<true ><<<dim3(8,64),256,0,stream>>>(xh,xl,1024, WvTh,WvTl,1024, bv, 1.f,
                                            nullptr,nullptr, vf, 1024,1024);
  gather_updates<<<512,256,0,stream>>>(tidx, tw, knp, vf, cath, catl);
  // q2 = x@Wq+bq (no relu) -> Region B (vf dead after gather)
  gemm3<false><<<dim3(8,64),256,0,stream>>>(xh,xl,1024, WqTh,WqTl,1024, bq, 1.f,
                                            q2h,q2l, nullptr, 1024,1024);
  // mlp: h1 = relu(cat@W1+b1) ; edges = h1@W2+b2 -> fp32 d_out + split for k2
  gemm3<true ><<<dim3(8,4),256,0,stream>>>(cath,catl,2048, W1Th,W1Tl,2048, b1, 1.f,
                                           h1h,h1l, nullptr, 2048,1024);
  gemm3<false><<<dim3(8,4),256,0,stream>>>(h1h,h1l,1024, W2Th,W2Tl,1024, b2, 1.f,
                                           eoh,eol, out_edges, 1024,1024);
  // k2 = relu(edges@Wk+bk)
  gemm3<true ><<<dim3(8,4),256,0,stream>>>(eoh,eol,1024, WkTh,WkTl,1024, bk, 1.f,
                                           k2h,k2l, nullptr, 1024,1024);
  // dots_v = q2@k2^T / 32 -> dotsf
  gemm3<false><<<dim3(4,64),256,0,stream>>>(q2h,q2l,1024, k2h,k2l,1024, nullptr, 0.03125f,
                                            nullptr,nullptr, dotsf, 1024,512);
  softmax_topk_h<<<8192,256,0,stream>>>(dotsf, kep, out_H);
}

// Round 6
// 629.763 us; speedup vs baseline: 2.4010x; 2.4010x over previous
//
#include <hip/hip_runtime.h>
#include <stdint.h>
#include <stddef.h>

typedef unsigned short u16;
typedef __bf16 bf16x8 __attribute__((ext_vector_type(8)));
typedef float f32x4 __attribute__((ext_vector_type(4)));

#define DEV __device__ __forceinline__

DEV float bf2f(u16 u){ union{uint32_t i; float f;} c; c.i=(uint32_t)u<<16; return c.f; }
DEV u16 f2bf(float f){ union{float f; uint32_t i;} c; c.f=f; uint32_t x=c.i;
  uint32_t r = x + 0x7FFFu + ((x>>16)&1u); return (u16)(r>>16); }
DEV uint32_t fmap(float f){ union{float f; uint32_t u;} c; c.f=f;
  return (c.u & 0x80000000u) ? ~c.u : (c.u | 0x80000000u); }
DEV float funmap(uint32_t u){ union{uint32_t u; float f;} c;
  c.u = (u & 0x80000000u) ? (u & 0x7FFFFFFFu) : ~u; return c.f; }
DEV void split2(float x, u16& h, u16& l){ h = f2bf(x); l = f2bf(x - bf2f(h)); }

// ---- block reductions (256 threads = 4 waves) ----
DEV float bredsum(float v, float* buf, int tid){
  #pragma unroll
  for(int o=32;o;o>>=1) v += __shfl_down(v,o);
  __syncthreads();
  if((tid&63)==0) buf[tid>>6]=v;
  __syncthreads();
  return buf[0]+buf[1]+buf[2]+buf[3];
}
DEV float bredmax(float v, float* buf, int tid){
  #pragma unroll
  for(int o=32;o;o>>=1) v = fmaxf(v, __shfl_down(v,o));
  __syncthreads();
  if((tid&63)==0) buf[tid>>6]=v;
  __syncthreads();
  return fmaxf(fmaxf(buf[0],buf[1]),fmaxf(buf[2],buf[3]));
}
DEV int bredsumi(int v, int* buf, int tid){
  #pragma unroll
  for(int o=32;o;o>>=1) v += __shfl_down(v,o);
  __syncthreads();
  if((tid&63)==0) buf[tid>>6]=v;
  __syncthreads();
  return buf[0]+buf[1]+buf[2]+buf[3];
}

// ============================================================================
// Plain bf16 GEMM: C[M,N] = act(scale * A@Bt^T + bias). 128x128 tile, BK=32,
// register-double-buffered staging (prefetch next K-tile during MFMA).
// ============================================================================
template<bool RELU>
__global__ __launch_bounds__(256)
void gemm1(const u16* __restrict__ A, int lda,
           const u16* __restrict__ Bt, int ldb,
           const float* __restrict__ bias, float scale,
           u16* __restrict__ outb, float* __restrict__ outf,
           int K, int ldc)
{
  __shared__ __align__(16) u16 As[128*32];
  __shared__ __align__(16) u16 Bs[128*32];
  const int tid = threadIdx.x, lane = tid&63, wave = tid>>6;
  const int m0 = blockIdx.y*128, n0 = blockIdx.x*128;
  const int wm=(wave>>1)*64, wn=(wave&1)*64;
  const int ml=lane&15, quad=lane>>4;
  const int c0 = tid, c1 = 256+tid;
  const u16* pa0 = A  + (size_t)(m0+(c0>>2))*lda + (c0&3)*8;
  const u16* pa1 = A  + (size_t)(m0+(c1>>2))*lda + (c1&3)*8;
  const u16* pb0 = Bt + (size_t)(n0+(c0>>2))*ldb + (c0&3)*8;
  const u16* pb1 = Bt + (size_t)(n0+(c1>>2))*ldb + (c1&3)*8;

  f32x4 acc[4][4];
  #pragma unroll
  for(int i=0;i<4;i++)
    #pragma unroll
    for(int j=0;j<4;j++) acc[i][j] = (f32x4){0.f,0.f,0.f,0.f};

  uint4 ra0=*(const uint4*)pa0, ra1=*(const uint4*)pa1;
  uint4 rb0=*(const uint4*)pb0, rb1=*(const uint4*)pb1;
  for(int k0=0;k0<K;k0+=32){
    __syncthreads();
    *(uint4*)&As[c0*8]=ra0; *(uint4*)&As[c1*8]=ra1;
    *(uint4*)&Bs[c0*8]=rb0; *(uint4*)&Bs[c1*8]=rb1;
    __syncthreads();
    if(k0+32<K){
      ra0=*(const uint4*)(pa0+k0+32); ra1=*(const uint4*)(pa1+k0+32);
      rb0=*(const uint4*)(pb0+k0+32); rb1=*(const uint4*)(pb1+k0+32);
    }
    bf16x8 af[4], bf[4];
    #pragma unroll
    for(int mi=0;mi<4;mi++) af[mi] = *(const bf16x8*)&As[(wm+mi*16+ml)*32 + quad*8];
    #pragma unroll
    for(int ni=0;ni<4;ni++) bf[ni] = *(const bf16x8*)&Bs[(wn+ni*16+ml)*32 + quad*8];
    #pragma unroll
    for(int mi=0;mi<4;mi++)
      #pragma unroll
      for(int ni=0;ni<4;ni++)
        acc[mi][ni] = __builtin_amdgcn_mfma_f32_16x16x32_bf16(af[mi], bf[ni], acc[mi][ni], 0,0,0);
  }
  // C/D: col = lane&15, row = quad*4 + reg  (m89-verified)
  #pragma unroll
  for(int mi=0;mi<4;mi++){
    const int rbase = m0 + wm + mi*16 + quad*4;
    #pragma unroll
    for(int ni=0;ni<4;ni++){
      const int col = n0 + wn + ni*16 + ml;
      const float bv = bias ? bias[col] : 0.f;
      #pragma unroll
      for(int r=0;r<4;r++){
        float v = acc[mi][ni][r]*scale + bv;
        if(RELU) v = fmaxf(v, 0.f);
        const size_t idx = (size_t)(rbase + r)*ldc + col;
        if(outb) outb[idx] = f2bf(v);
        if(outf) outf[idx] = v;
      }
    }
  }
}

// ============================================================================
// Split-bf16 GEMM (fp32-class): 3 MFMAs/step (hh+hl+lh), same tile/prefetch.
// ============================================================================
template<bool RELU>
__global__ __launch_bounds__(256)
void gemm3(const u16* __restrict__ Ah, const u16* __restrict__ Al, int lda,
           const u16* __restrict__ Bh, const u16* __restrict__ Bl, int ldb,
           const float* __restrict__ bias, float scale,
           u16* __restrict__ outh, u16* __restrict__ outl,
           float* __restrict__ outf,
           int K, int ldc)
{
  __shared__ __align__(16) u16 AsH[128*32];
  __shared__ __align__(16) u16 AsL[128*32];
  __shared__ __align__(16) u16 BsH[128*32];
  __shared__ __align__(16) u16 BsL[128*32];
  const int tid = threadIdx.x, lane = tid&63, wave = tid>>6;
  const int m0 = blockIdx.y*128, n0 = blockIdx.x*128;
  const int wm=(wave>>1)*64, wn=(wave&1)*64;
  const int ml=lane&15, quad=lane>>4;
  const int c0 = tid, c1 = 256+tid;
  const size_t ao0 = (size_t)(m0+(c0>>2))*lda + (c0&3)*8;
  const size_t ao1 = (size_t)(m0+(c1>>2))*lda + (c1&3)*8;
  const size_t bo0 = (size_t)(n0+(c0>>2))*ldb + (c0&3)*8;
  const size_t bo1 = (size_t)(n0+(c1>>2))*ldb + (c1&3)*8;

  f32x4 acc[4][4];
  #pragma unroll
  for(int i=0;i<4;i++)
    #pragma unroll
    for(int j=0;j<4;j++) acc[i][j] = (f32x4){0.f,0.f,0.f,0.f};

  uint4 rah0=*(const uint4*)(Ah+ao0), rah1=*(const uint4*)(Ah+ao1);
  uint4 ral0=*(const uint4*)(Al+ao0), ral1=*(const uint4*)(Al+ao1);
  uint4 rbh0=*(const uint4*)(Bh+bo0), rbh1=*(const uint4*)(Bh+bo1);
  uint4 rbl0=*(const uint4*)(Bl+bo0), rbl1=*(const uint4*)(Bl+bo1);
  for(int k0=0;k0<K;k0+=32){
    __syncthreads();
    *(uint4*)&AsH[c0*8]=rah0; *(uint4*)&AsH[c1*8]=rah1;
    *(uint4*)&AsL[c0*8]=ral0; *(uint4*)&AsL[c1*8]=ral1;
    *(uint4*)&BsH[c0*8]=rbh0; *(uint4*)&BsH[c1*8]=rbh1;
    *(uint4*)&BsL[c0*8]=rbl0; *(uint4*)&BsL[c1*8]=rbl1;
    __syncthreads();
    if(k0+32<K){
      const int s = k0+32;
      rah0=*(const uint4*)(Ah+ao0+s); rah1=*(const uint4*)(Ah+ao1+s);
      ral0=*(const uint4*)(Al+ao0+s); ral1=*(const uint4*)(Al+ao1+s);
      rbh0=*(const uint4*)(Bh+bo0+s); rbh1=*(const uint4*)(Bh+bo1+s);
      rbl0=*(const uint4*)(Bl+bo0+s); rbl1=*(const uint4*)(Bl+bo1+s);
    }
    bf16x8 afh[4], afl[4], bfh[4], bfl[4];
    #pragma unroll
    for(int mi=0;mi<4;mi++){
      const int o = (wm+mi*16+ml)*32 + quad*8;
      afh[mi] = *(const bf16x8*)&AsH[o];
      afl[mi] = *(const bf16x8*)&AsL[o];
    }
    #pragma unroll
    for(int ni=0;ni<4;ni++){
      const int o = (wn+ni*16+ml)*32 + quad*8;
      bfh[ni] = *(const bf16x8*)&BsH[o];
      bfl[ni] = *(const bf16x8*)&BsL[o];
    }
    #pragma unroll
    for(int mi=0;mi<4;mi++)
      #pragma unroll
      for(int ni=0;ni<4;ni++){
        acc[mi][ni] = __builtin_amdgcn_mfma_f32_16x16x32_bf16(afh[mi], bfh[ni], acc[mi][ni], 0,0,0);
        acc[mi][ni] = __builtin_amdgcn_mfma_f32_16x16x32_bf16(afh[mi], bfl[ni], acc[mi][ni], 0,0,0);
        acc[mi][ni] = __builtin_amdgcn_mfma_f32_16x16x32_bf16(afl[mi], bfh[ni], acc[mi][ni], 0,0,0);
      }
  }
  #pragma unroll
  for(int mi=0;mi<4;mi++){
    const int rbase = m0 + wm + mi*16 + quad*4;
    #pragma unroll
    for(int ni=0;ni<4;ni++){
      const int col = n0 + wn + ni*16 + ml;
      const float bv = bias ? bias[col] : 0.f;
      #pragma unroll
      for(int r=0;r<4;r++){
        float v = acc[mi][ni][r]*scale + bv;
        if(RELU) v = fmaxf(v, 0.f);
        const size_t idx = (size_t)(rbase + r)*ldc + col;
        if(outh){
          u16 h, l; split2(v, h, l);
          outh[idx] = h; outl[idx] = l;
        }
        if(outf) outf[idx] = v;
      }
    }
  }
}

// ============================================================================
// fp32 transpose -> split-bf16 / plain-bf16
// ============================================================================
__global__ __launch_bounds__(256)
void transpose_split(const float* __restrict__ in, u16* __restrict__ outh,
                     u16* __restrict__ outl, int R, int C)
{
  __shared__ float tile[32][33];
  const int tx = threadIdx.x & 31, ty = threadIdx.x >> 5;
  const int bx = blockIdx.x*32, by = blockIdx.y*32;
  #pragma unroll
  for(int i=0;i<32;i+=8)
    tile[ty+i][tx] = in[(size_t)(by+ty+i)*C + bx + tx];
  __syncthreads();
  #pragma unroll
  for(int i=0;i<32;i+=8){
    const float v = tile[tx][ty+i];
    u16 h, l; split2(v, h, l);
    const size_t o = (size_t)(bx+ty+i)*R + by + tx;
    outh[o] = h; outl[o] = l;
  }
}
__global__ __launch_bounds__(256)
void transpose_plain(const float* __restrict__ in, u16* __restrict__ outh, int R, int C)
{
  __shared__ float tile[32][33];
  const int tx = threadIdx.x & 31, ty = threadIdx.x >> 5;
  const int bx = blockIdx.x*32, by = blockIdx.y*32;
  #pragma unroll
  for(int i=0;i<32;i+=8)
    tile[ty+i][tx] = in[(size_t)(by+ty+i)*C + bx + tx];
  __syncthreads();
  #pragma unroll
  for(int i=0;i<32;i+=8)
    outh[(size_t)(bx+ty+i)*R + by + tx] = f2bf(tile[tx][ty+i]);
}
// fp32 -> split-bf16, no transpose (for raw Wq used in the Gt trick)
__global__ __launch_bounds__(256)
void split_convert(const float* __restrict__ in, u16* __restrict__ oh,
                   u16* __restrict__ ol)
{
  const int i = blockIdx.x*256 + threadIdx.x;
  const float4 v = ((const float4*)in)[i];
  ushort4 h4, l4;
  split2(v.x, h4.x, l4.x); split2(v.y, h4.y, l4.y);
  split2(v.z, h4.z, l4.z); split2(v.w, h4.w, l4.w);
  ((ushort4*)oh)[i] = h4; ((ushort4*)ol)[i] = l4;
}

// ============================================================================
// LayerNorm D=1024 fp32 in -> split-bf16 out
// ============================================================================
__global__ __launch_bounds__(256)
void layernorm_rows(const float* __restrict__ in, const float* __restrict__ g,
                    const float* __restrict__ bb, u16* __restrict__ outh,
                    u16* __restrict__ outl, int ostride)
{
  __shared__ float buf[4];
  const int row = blockIdx.x, tid = threadIdx.x;
  const float4 xv = ((const float4*)(in + (size_t)row*1024))[tid];
  float s  = bredsum(xv.x+xv.y+xv.z+xv.w, buf, tid);
  float s2 = bredsum(xv.x*xv.x+xv.y*xv.y+xv.z*xv.z+xv.w*xv.w, buf, tid);
  const float mean = s * (1.f/1024.f);
  const float var  = s2 * (1.f/1024.f) - mean*mean;
  const float rs   = 1.f / sqrtf(var + 1e-5f);
  const float4 gv = ((const float4*)g)[tid];
  const float4 bv = ((const float4*)bb)[tid];
  float o0 = (xv.x-mean)*rs*gv.x + bv.x;
  float o1 = (xv.y-mean)*rs*gv.y + bv.y;
  float o2 = (xv.z-mean)*rs*gv.z + bv.z;
  float o3 = (xv.w-mean)*rs*gv.w + bv.w;
  ushort4 oh, ol;
  split2(o0, oh.x, ol.x); split2(o1, oh.y, ol.y);
  split2(o2, oh.z, ol.z); split2(o3, oh.w, ol.w);
  ((ushort4*)(outh + (size_t)row*ostride))[tid] = oh;
  ((ushort4*)(outl + (size_t)row*ostride))[tid] = ol;
}

__global__ __launch_bounds__(256)
void edges_ln(const float* __restrict__ noise, const float* __restrict__ mu,
              const float* __restrict__ lsig, const float* __restrict__ g,
              const float* __restrict__ bb, u16* __restrict__ outh,
              u16* __restrict__ outl, int ostride)
{
  __shared__ float buf[4];
  const int row = blockIdx.x, tid = threadIdx.x;
  const float4 nv  = ((const float4*)(noise + (size_t)row*1024))[tid];
  const float4 muv = ((const float4*)mu)[tid];
  const float4 lsv = ((const float4*)lsig)[tid];
  float v0 = muv.x + expf(lsv.x)*nv.x;
  float v1 = muv.y + expf(lsv.y)*nv.y;
  float v2 = muv.z + expf(lsv.z)*nv.z;
  float v3 = muv.w + expf(lsv.w)*nv.w;
  float s  = bredsum(v0+v1+v2+v3, buf, tid);
  float s2 = bredsum(v0*v0+v1*v1+v2*v2+v3*v3, buf, tid);
  const float mean = s * (1.f/1024.f);
  const float var  = s2 * (1.f/1024.f) - mean*mean;
  const float rs   = 1.f / sqrtf(var + 1e-5f);
  const float4 gv = ((const float4*)g)[tid];
  const float4 bv = ((const float4*)bb)[tid];
  float o0 = (v0-mean)*rs*gv.x + bv.x;
  float o1 = (v1-mean)*rs*gv.y + bv.y;
  float o2 = (v2-mean)*rs*gv.z + bv.z;
  float o3 = (v3-mean)*rs*gv.w + bv.w;
  ushort4 oh, ol;
  split2(o0, oh.x, ol.x); split2(o1, oh.y, ol.y);
  split2(o2, oh.z, ol.z); split2(o3, oh.w, ol.w);
  ((ushort4*)(outh + (size_t)row*ostride))[tid] = oh;
  ((ushort4*)(outl + (size_t)row*ostride))[tid] = ol;
}

// ============================================================================
// softmax(8192)+eps+renorm + top-k_n -> (idx, weight) pairs. 1 block/row.
// ============================================================================
#define USI(i) ((i) + ((i)>>5))
__global__ __launch_bounds__(256)
void softmax_topk_a(const float* __restrict__ dots, const int* __restrict__ knp,
                    int* __restrict__ tidx, float* __restrict__ tw)
{
  const int NC = 8192;
  __shared__ uint32_t us[8192 + 256];
  __shared__ float fbuf[4];
  __shared__ int ibuf[4];
  __shared__ int scan[256];
  __shared__ int slot_ctr;
  const int row = blockIdx.x, tid = threadIdx.x;
  const float* x = dots + (size_t)row * NC;

  float mx = -3.4e38f;
  for(int i=tid;i<NC;i+=256){ float f = x[i]; us[USI(i)] = fmap(f); mx = fmaxf(mx, f); }
  mx = bredmax(mx, fbuf, tid);
  float se = 0.f;
  for(int i=tid;i<NC;i+=256) se += expf(funmap(us[USI(i)]) - mx);
  se = bredsum(se, fbuf, tid);
  float ts = 0.f;
  for(int i=tid;i<NC;i+=256) ts += expf(funmap(us[USI(i)]) - mx)/se + 1e-8f;
  const float T = bredsum(ts, fbuf, tid);

  const int k = knp[0];
  uint32_t lo = 0u, hi = 0xFFFFFFFFu;
  const int base = tid*32;
  while(lo < hi){
    const uint32_t mid = lo + ((hi - lo) >> 1) + 1u;
    int c = 0;
    #pragma unroll 8
    for(int j=0;j<32;j++) c += (us[USI(base+j)] >= mid);
    c = bredsumi(c, ibuf, tid);
    if(c >= k) lo = mid; else hi = mid - 1u;
  }
  const uint32_t uth = lo;
  int gt = 0, eq = 0;
  #pragma unroll 8
  for(int j=0;j<32;j++){ uint32_t u = us[USI(base+j)]; gt += (u>uth); eq += (u==uth); }
  const int c1 = bredsumi(gt, ibuf, tid);
  __syncthreads();
  scan[tid] = eq;
  __syncthreads();
  #pragma unroll
  for(int o=1;o<256;o<<=1){
    int t = (tid>=o) ? scan[tid-o] : 0;
    __syncthreads();
    scan[tid] += t;
    __syncthreads();
  }
  int eq_rank = scan[tid] - eq;
  const int budget = k - c1;
  if(tid==0) slot_ctr = 0;
  __syncthreads();
  for(int j=0;j<32;j++){
    const int i = base + j;
    const uint32_t u = us[USI(i)];
    bool sel = (u > uth);
    if(u == uth){ sel = (eq_rank < budget); eq_rank++; }
    if(sel){
      const int s = atomicAdd(&slot_ctr, 1);
      const float f = funmap(u);
      const float w = (expf(f - mx)/se + 1e-8f) / T;
      if(s < 128){ tidx[row*128 + s] = i; tw[row*128 + s] = w; }
    }
  }
}

// updates[row] = sum_j w_j * v[idx_j] (v bf16) ; split-bf16 into cat[:,1024:]
__global__ __launch_bounds__(256)
void gather_updates(const int* __restrict__ tidx, const float* __restrict__ tw,
                    const int* __restrict__ knp, const u16* __restrict__ v,
                    u16* __restrict__ cath, u16* __restrict__ catl)
{
  __shared__ int   idx_s[128];
  __shared__ float w_s[128];
  const int row = blockIdx.x, tid = threadIdx.x;
  const int kk = knp[0];
  if(tid < 128){
    idx_s[tid] = (tid < kk) ? (tidx[row*128+tid] & 8191) : 0;
    w_s[tid]   = (tid < kk) ? tw[row*128+tid] : 0.f;
  }
  __syncthreads();
  const int c = tid*4;
  float a0=0,a1=0,a2=0,a3=0;
  for(int j=0;j<kk && j<128;j++){
    const ushort4 vv = *(const ushort4*)&v[(size_t)idx_s[j]*1024 + c];
    const float w = w_s[j];
    a0 += w*bf2f(vv.x); a1 += w*bf2f(vv.y); a2 += w*bf2f(vv.z); a3 += w*bf2f(vv.w);
  }
  ushort4 oh, ol;
  split2(a0, oh.x, ol.x); split2(a1, oh.y, ol.y);
  split2(a2, oh.z, ol.z); split2(a3, oh.w, ol.w);
  ((ushort4*)(cath + (size_t)row*2048 + 1024))[tid] = oh;
  ((ushort4*)(catl + (size_t)row*2048 + 1024))[tid] = ol;
}

// bias_v[m] = dot(bq, k2[m]) / 32   (k2 = split-bf16)
__global__ __launch_bounds__(256)
void bias_v_kernel(const float* __restrict__ bq, const u16* __restrict__ k2h,
                   const u16* __restrict__ k2l, float* __restrict__ out)
{
  __shared__ float buf[4];
  const int row = blockIdx.x, tid = threadIdx.x;
  const ushort4 h4 = ((const ushort4*)(k2h + (size_t)row*1024))[tid];
  const ushort4 l4 = ((const ushort4*)(k2l + (size_t)row*1024))[tid];
  const float4 b4 = ((const float4*)bq)[tid];
  float s = b4.x*(bf2f(h4.x)+bf2f(l4.x)) + b4.y*(bf2f(h4.y)+bf2f(l4.y))
          + b4.z*(bf2f(h4.z)+bf2f(l4.z)) + b4.w*(bf2f(h4.w)+bf2f(l4.w));
  s = bredsum(s, buf, tid);
  if(tid==0) out[row] = s * 0.03125f;
}

// ============================================================================
// H: softmax over 512 per row, keep top-k_e, zeros elsewhere. fp32 out.
// ============================================================================
__global__ __launch_bounds__(256)
void softmax_topk_h(const float* __restrict__ dv, const int* __restrict__ kep,
                    float* __restrict__ H)
{
  __shared__ float fbuf[4];
  __shared__ int ibuf[4];
  __shared__ int scan[256];
  const int row = blockIdx.x, tid = threadIdx.x;
  const float2 fv = ((const float2*)(dv + (size_t)row*512))[tid];
  const float f0 = fv.x, f1 = fv.y;
  const float mx = bredmax(fmaxf(f0,f1), fbuf, tid);
  const float e0 = expf(f0-mx), e1 = expf(f1-mx);
  const float se = bredsum(e0+e1, fbuf, tid);
  const float p0 = e0/se, p1 = e1/se;
  const uint32_t u0 = fmap(f0), u1 = fmap(f1);
  const int k = kep[0];
  uint32_t lo = 0u, hi = 0xFFFFFFFFu;
  while(lo < hi){
    const uint32_t mid = lo + ((hi - lo) >> 1) + 1u;
    int c = (u0 >= mid) + (u1 >= mid);
    c = bredsumi(c, ibuf, tid);
    if(c >= k) lo = mid; else hi = mid - 1u;
  }
  const uint32_t uth = lo;
  const int gt = (u0>uth) + (u1>uth);
  const int eq = (u0==uth) + (u1==uth);
  const int c1 = bredsumi(gt, ibuf, tid);
  __syncthreads();
  scan[tid] = eq;
  __syncthreads();
  #pragma unroll
  for(int o=1;o<256;o<<=1){
    int t = (tid>=o) ? scan[tid-o] : 0;
    __syncthreads();
    scan[tid] += t;
    __syncthreads();
  }
  const int eq_before = scan[tid] - eq;
  const int budget = k - c1;
  const bool s0 = (u0>uth) || ((u0==uth) && (eq_before < budget));
  const bool s1 = (u1>uth) || ((u1==uth) && (eq_before + (u0==uth?1:0) < budget));
  float2 o;
  o.x = s0 ? p0 : 0.f;
  o.y = s1 ? p1 : 0.f;
  ((float2*)(H + (size_t)row*512))[tid] = o;
}

// ============================================================================
extern "C" void kernel_launch(void* const* d_in, const int* in_sizes, int n_in,
                              void* d_out, int out_size, void* d_ws, size_t ws_size,
                              hipStream_t stream)
{
  const float* inputs = (const float*)d_in[0];
  const float* noise  = (const float*)d_in[1];
  const float* emu    = (const float*)d_in[2];
  const float* elsig  = (const float*)d_in[3];
  const float* Wq = (const float*)d_in[4];  const float* bq = (const float*)d_in[5];
  const float* Wk = (const float*)d_in[6];  const float* bk = (const float*)d_in[7];
  const float* Wv = (const float*)d_in[8];  const float* bv = (const float*)d_in[9];
  const float* W1 = (const float*)d_in[10]; const float* b1 = (const float*)d_in[11];
  const float* W2 = (const float*)d_in[12]; const float* b2 = (const float*)d_in[13];
  const float* g_in = (const float*)d_in[14]; const float* b_in = (const float*)d_in[15];
  const float* g_e  = (const float*)d_in[16]; const float* b_e  = (const float*)d_in[17];
  const int* knp = (const int*)d_in[18];
  const int* kep = (const int*)d_in[19];

  float* out = (float*)d_out;
  float* out_edges = out;                             // 512*1024
  float* out_H     = out + 512*1024;                  // 8192*512
  float* out_dots  = out + 512*1024 + 8192*512;       // 512*8192

  // ---- workspace (~102 MB peak, stream-ordered reuse) ----
  char* p = (char*)d_ws;
  const size_t MB = 1024ull*1024;
  u16* xh = (u16*)(p + 0*MB);            // x split, live to the end (dots_v)
  u16* xl = (u16*)(p + 16*MB);
  u16* kb = (u16*)(p + 32*MB);           // k bf16, dead after dots GEMM
  u16* vb = (u16*)(p + 48*MB);           // v bf16, dead after gather
  float* dotsvf = (float*)(p + 32*MB);   // dots_v fp32 (reuses kb region)
  // weights [64,88)
  u16* WkTh = (u16*)(p + 64*MB);  u16* WkTl = (u16*)(p + 66*MB);
  u16* WvTh = (u16*)(p + 68*MB);
  u16* WqTh = (u16*)(p + 70*MB);
  u16* Wqh  = (u16*)(p + 72*MB);  u16* Wql  = (u16*)(p + 74*MB);   // raw (no T)
  u16* W1Th = (u16*)(p + 76*MB);  u16* W1Tl = (u16*)(p + 80*MB);
  u16* W2Th = (u16*)(p + 84*MB);  u16* W2Tl = (u16*)(p + 86*MB);
  // small [88,102)
  u16* cath = (u16*)(p + 88*MB);  u16* catl = (u16*)(p + 90*MB);
  u16* qmb  = (u16*)(p + 92*MB);
  u16* h1h  = (u16*)(p + 93*MB);  u16* h1l  = (u16*)(p + 94*MB);
  u16* eoh  = (u16*)(p + 95*MB);  u16* eol  = (u16*)(p + 96*MB);
  u16* k2h  = (u16*)(p + 97*MB);  u16* k2l  = (u16*)(p + 98*MB);
  u16* Gth  = (u16*)(p + 99*MB);  u16* Gtl  = (u16*)(p + 100*MB);
  int*   tidx  = (int*)  (p + 101*MB);
  float* tw    = (float*)(p + 101*MB + 256*1024);
  float* biasv = (float*)(p + 101*MB + 512*1024);

  hipMemsetAsync(tidx, 0, 512ull*128*4, stream);
  hipMemsetAsync(tw,   0, 512ull*128*4, stream);

  // weight prep
  transpose_split<<<dim3(32,32),256,0,stream>>>(Wk, WkTh, WkTl, 1024, 1024);
  transpose_split<<<dim3(32,64),256,0,stream>>>(W1, W1Th, W1Tl, 2048, 1024);
  transpose_split<<<dim3(32,32),256,0,stream>>>(W2, W2Th, W2Tl, 1024, 1024);
  transpose_plain<<<dim3(32,32),256,0,stream>>>(Wv, WvTh, 1024, 1024);
  transpose_plain<<<dim3(32,32),256,0,stream>>>(Wq, WqTh, 1024, 1024);
  split_convert<<<1024,256,0,stream>>>(Wq, Wqh, Wql);

  layernorm_rows<<<8192,256,0,stream>>>(inputs, g_in, b_in, xh, xl, 1024);
  edges_ln<<<512,256,0,stream>>>(noise, emu, elsig, g_e, b_e, cath, catl, 2048);

  // --- dots chain (plain bf16; selection-tolerant) ---
  gemm1<true ><<<dim3(8,64),256,0,stream>>>(xh,1024, WkTh,1024, bk, 1.f,
                                            kb,nullptr, 1024,1024);
  gemm1<true ><<<dim3(8,64),256,0,stream>>>(xh,1024, WvTh,1024, bv, 1.f,
                                            vb,nullptr, 1024,1024);
  gemm1<true ><<<dim3(8,4),256,0,stream>>>(cath,2048, WqTh,1024, bq, 1.f,
                                           qmb,nullptr, 1024,1024);
  gemm1<false><<<dim3(64,4),256,0,stream>>>(qmb,1024, kb,1024, nullptr, 0.03125f,
                                            nullptr,out_dots, 1024,8192);
  softmax_topk_a<<<512,256,0,stream>>>(out_dots, knp, tidx, tw);
  gather_updates<<<512,256,0,stream>>>(tidx, tw, knp, vb, cath, catl);

  // --- edges + H chain (split-bf16, fp32-class) ---
  gemm3<true ><<<dim3(8,4),256,0,stream>>>(cath,catl,2048, W1Th,W1Tl,2048, b1, 1.f,
                                           h1h,h1l, nullptr, 2048,1024);
  gemm3<false><<<dim3(8,4),256,0,stream>>>(h1h,h1l,1024, W2Th,W2Tl,1024, b2, 1.f,
                                           eoh,eol, out_edges, 1024,1024);
  gemm3<true ><<<dim3(8,4),256,0,stream>>>(eoh,eol,1024, WkTh,WkTl,1024, bk, 1.f,
                                           k2h,k2l, nullptr, 1024,1024);
  // Gt[m,e] = sum_d k2[m,d] * Wq[e,d]  (associativity: dots_v = x@Gt^T/32 + bias)
  gemm3<false><<<dim3(8,4),256,0,stream>>>(k2h,k2l,1024, Wqh,Wql,1024, nullptr, 1.f,
                                           Gth,Gtl, nullptr, 1024,1024);
  bias_v_kernel<<<512,256,0,stream>>>(bq, k2h, k2l, biasv);
  gemm3<false><<<dim3(4,64),256,0,stream>>>(xh,xl,1024, Gth,Gtl,1024, biasv, 0.03125f,
                                            nullptr,nullptr, dotsvf, 1024,512);
  softmax_topk_h<<<8192,256,0,stream>>>(dotsvf, kep, out_H);
}

// Round 7
// 551.025 us; speedup vs baseline: 2.7441x; 1.1429x over previous
//
#include <hip/hip_runtime.h>
#include <stdint.h>
#include <stddef.h>

typedef unsigned short u16;
typedef __bf16 bf16x8 __attribute__((ext_vector_type(8)));
typedef float f32x4 __attribute__((ext_vector_type(4)));

#define DEV __device__ __forceinline__

DEV float bf2f(u16 u){ union{uint32_t i; float f;} c; c.i=(uint32_t)u<<16; return c.f; }
DEV u16 f2bf(float f){ union{float f; uint32_t i;} c; c.f=f; uint32_t x=c.i;
  uint32_t r = x + 0x7FFFu + ((x>>16)&1u); return (u16)(r>>16); }
DEV uint32_t fmap(float f){ union{float f; uint32_t u;} c; c.f=f;
  return (c.u & 0x80000000u) ? ~c.u : (c.u | 0x80000000u); }
DEV float funmap(uint32_t u){ union{uint32_t u; float f;} c;
  c.u = (u & 0x80000000u) ? (u & 0x7FFFFFFFu) : ~u; return c.f; }
DEV void split2(float x, u16& h, u16& l){ h = f2bf(x); l = f2bf(x - bf2f(h)); }

// ---- block reductions (256 threads = 4 waves) ----
DEV float bredsum(float v, float* buf, int tid){
  #pragma unroll
  for(int o=32;o;o>>=1) v += __shfl_down(v,o);
  __syncthreads();
  if((tid&63)==0) buf[tid>>6]=v;
  __syncthreads();
  return buf[0]+buf[1]+buf[2]+buf[3];
}
DEV float bredmax(float v, float* buf, int tid){
  #pragma unroll
  for(int o=32;o;o>>=1) v = fmaxf(v, __shfl_down(v,o));
  __syncthreads();
  if((tid&63)==0) buf[tid>>6]=v;
  __syncthreads();
  return fmaxf(fmaxf(buf[0],buf[1]),fmaxf(buf[2],buf[3]));
}
DEV int bredsumi(int v, int* buf, int tid){
  #pragma unroll
  for(int o=32;o;o>>=1) v += __shfl_down(v,o);
  __syncthreads();
  if((tid&63)==0) buf[tid>>6]=v;
  __syncthreads();
  return buf[0]+buf[1]+buf[2]+buf[3];
}

// ============================================================================
// Plain bf16 GEMM: C[M,N] = act(scale * A@Bt^T + bias). 128x128 tile, BK=32,
// register-double-buffered staging (prefetch next K-tile during MFMA).
// ============================================================================
template<bool RELU>
__global__ __launch_bounds__(256)
void gemm1(const u16* __restrict__ A, int lda,
           const u16* __restrict__ Bt, int ldb,
           const float* __restrict__ bias, float scale,
           u16* __restrict__ outb, float* __restrict__ outf,
           int K, int ldc)
{
  __shared__ __align__(16) u16 As[128*32];
  __shared__ __align__(16) u16 Bs[128*32];
  const int tid = threadIdx.x, lane = tid&63, wave = tid>>6;
  const int m0 = blockIdx.y*128, n0 = blockIdx.x*128;
  const int wm=(wave>>1)*64, wn=(wave&1)*64;
  const int ml=lane&15, quad=lane>>4;
  const int c0 = tid, c1 = 256+tid;
  const u16* pa0 = A  + (size_t)(m0+(c0>>2))*lda + (c0&3)*8;
  const u16* pa1 = A  + (size_t)(m0+(c1>>2))*lda + (c1&3)*8;
  const u16* pb0 = Bt + (size_t)(n0+(c0>>2))*ldb + (c0&3)*8;
  const u16* pb1 = Bt + (size_t)(n0+(c1>>2))*ldb + (c1&3)*8;

  f32x4 acc[4][4];
  #pragma unroll
  for(int i=0;i<4;i++)
    #pragma unroll
    for(int j=0;j<4;j++) acc[i][j] = (f32x4){0.f,0.f,0.f,0.f};

  uint4 ra0=*(const uint4*)pa0, ra1=*(const uint4*)pa1;
  uint4 rb0=*(const uint4*)pb0, rb1=*(const uint4*)pb1;
  for(int k0=0;k0<K;k0+=32){
    __syncthreads();
    *(uint4*)&As[c0*8]=ra0; *(uint4*)&As[c1*8]=ra1;
    *(uint4*)&Bs[c0*8]=rb0; *(uint4*)&Bs[c1*8]=rb1;
    __syncthreads();
    if(k0+32<K){
      ra0=*(const uint4*)(pa0+k0+32); ra1=*(const uint4*)(pa1+k0+32);
      rb0=*(const uint4*)(pb0+k0+32); rb1=*(const uint4*)(pb1+k0+32);
    }
    bf16x8 af[4], bf[4];
    #pragma unroll
    for(int mi=0;mi<4;mi++) af[mi] = *(const bf16x8*)&As[(wm+mi*16+ml)*32 + quad*8];
    #pragma unroll
    for(int ni=0;ni<4;ni++) bf[ni] = *(const bf16x8*)&Bs[(wn+ni*16+ml)*32 + quad*8];
    #pragma unroll
    for(int mi=0;mi<4;mi++)
      #pragma unroll
      for(int ni=0;ni<4;ni++)
        acc[mi][ni] = __builtin_amdgcn_mfma_f32_16x16x32_bf16(af[mi], bf[ni], acc[mi][ni], 0,0,0);
  }
  // C/D: col = lane&15, row = quad*4 + reg  (m89-verified)
  #pragma unroll
  for(int mi=0;mi<4;mi++){
    const int rbase = m0 + wm + mi*16 + quad*4;
    #pragma unroll
    for(int ni=0;ni<4;ni++){
      const int col = n0 + wn + ni*16 + ml;
      const float bv = bias ? bias[col] : 0.f;
      #pragma unroll
      for(int r=0;r<4;r++){
        float v = acc[mi][ni][r]*scale + bv;
        if(RELU) v = fmaxf(v, 0.f);
        const size_t idx = (size_t)(rbase + r)*ldc + col;
        if(outb) outb[idx] = f2bf(v);
        if(outf) outf[idx] = v;
      }
    }
  }
}

// ============================================================================
// Split-bf16 GEMM (fp32-class): 3 MFMAs/step (hh+hl+lh), same tile/prefetch.
// ============================================================================
template<bool RELU>
__global__ __launch_bounds__(256)
void gemm3(const u16* __restrict__ Ah, const u16* __restrict__ Al, int lda,
           const u16* __restrict__ Bh, const u16* __restrict__ Bl, int ldb,
           const float* __restrict__ bias, float scale,
           u16* __restrict__ outh, u16* __restrict__ outl,
           float* __restrict__ outf,
           int K, int ldc)
{
  __shared__ __align__(16) u16 AsH[128*32];
  __shared__ __align__(16) u16 AsL[128*32];
  __shared__ __align__(16) u16 BsH[128*32];
  __shared__ __align__(16) u16 BsL[128*32];
  const int tid = threadIdx.x, lane = tid&63, wave = tid>>6;
  const int m0 = blockIdx.y*128, n0 = blockIdx.x*128;
  const int wm=(wave>>1)*64, wn=(wave&1)*64;
  const int ml=lane&15, quad=lane>>4;
  const int c0 = tid, c1 = 256+tid;
  const size_t ao0 = (size_t)(m0+(c0>>2))*lda + (c0&3)*8;
  const size_t ao1 = (size_t)(m0+(c1>>2))*lda + (c1&3)*8;
  const size_t bo0 = (size_t)(n0+(c0>>2))*ldb + (c0&3)*8;
  const size_t bo1 = (size_t)(n0+(c1>>2))*ldb + (c1&3)*8;

  f32x4 acc[4][4];
  #pragma unroll
  for(int i=0;i<4;i++)
    #pragma unroll
    for(int j=0;j<4;j++) acc[i][j] = (f32x4){0.f,0.f,0.f,0.f};

  uint4 rah0=*(const uint4*)(Ah+ao0), rah1=*(const uint4*)(Ah+ao1);
  uint4 ral0=*(const uint4*)(Al+ao0), ral1=*(const uint4*)(Al+ao1);
  uint4 rbh0=*(const uint4*)(Bh+bo0), rbh1=*(const uint4*)(Bh+bo1);
  uint4 rbl0=*(const uint4*)(Bl+bo0), rbl1=*(const uint4*)(Bl+bo1);
  for(int k0=0;k0<K;k0+=32){
    __syncthreads();
    *(uint4*)&AsH[c0*8]=rah0; *(uint4*)&AsH[c1*8]=rah1;
    *(uint4*)&AsL[c0*8]=ral0; *(uint4*)&AsL[c1*8]=ral1;
    *(uint4*)&BsH[c0*8]=rbh0; *(uint4*)&BsH[c1*8]=rbh1;
    *(uint4*)&BsL[c0*8]=rbl0; *(uint4*)&BsL[c1*8]=rbl1;
    __syncthreads();
    if(k0+32<K){
      const int s = k0+32;
      rah0=*(const uint4*)(Ah+ao0+s); rah1=*(const uint4*)(Ah+ao1+s);
      ral0=*(const uint4*)(Al+ao0+s); ral1=*(const uint4*)(Al+ao1+s);
      rbh0=*(const uint4*)(Bh+bo0+s); rbh1=*(const uint4*)(Bh+bo1+s);
      rbl0=*(const uint4*)(Bl+bo0+s); rbl1=*(const uint4*)(Bl+bo1+s);
    }
    bf16x8 afh[4], afl[4], bfh[4], bfl[4];
    #pragma unroll
    for(int mi=0;mi<4;mi++){
      const int o = (wm+mi*16+ml)*32 + quad*8;
      afh[mi] = *(const bf16x8*)&AsH[o];
      afl[mi] = *(const bf16x8*)&AsL[o];
    }
    #pragma unroll
    for(int ni=0;ni<4;ni++){
      const int o = (wn+ni*16+ml)*32 + quad*8;
      bfh[ni] = *(const bf16x8*)&BsH[o];
      bfl[ni] = *(const bf16x8*)&BsL[o];
    }
    #pragma unroll
    for(int mi=0;mi<4;mi++)
      #pragma unroll
      for(int ni=0;ni<4;ni++){
        acc[mi][ni] = __builtin_amdgcn_mfma_f32_16x16x32_bf16(afh[mi], bfh[ni], acc[mi][ni], 0,0,0);
        acc[mi][ni] = __builtin_amdgcn_mfma_f32_16x16x32_bf16(afh[mi], bfl[ni], acc[mi][ni], 0,0,0);
        acc[mi][ni] = __builtin_amdgcn_mfma_f32_16x16x32_bf16(afl[mi], bfh[ni], acc[mi][ni], 0,0,0);
      }
  }
  #pragma unroll
  for(int mi=0;mi<4;mi++){
    const int rbase = m0 + wm + mi*16 + quad*4;
    #pragma unroll
    for(int ni=0;ni<4;ni++){
      const int col = n0 + wn + ni*16 + ml;
      const float bv = bias ? bias[col] : 0.f;
      #pragma unroll
      for(int r=0;r<4;r++){
        float v = acc[mi][ni][r]*scale + bv;
        if(RELU) v = fmaxf(v, 0.f);
        const size_t idx = (size_t)(rbase + r)*ldc + col;
        if(outh){
          u16 h, l; split2(v, h, l);
          outh[idx] = h; outl[idx] = l;
        }
        if(outf) outf[idx] = v;
      }
    }
  }
}

// ============================================================================
// fp32 transpose -> split-bf16 / plain-bf16
// ============================================================================
__global__ __launch_bounds__(256)
void transpose_split(const float* __restrict__ in, u16* __restrict__ outh,
                     u16* __restrict__ outl, int R, int C)
{
  __shared__ float tile[32][33];
  const int tx = threadIdx.x & 31, ty = threadIdx.x >> 5;
  const int bx = blockIdx.x*32, by = blockIdx.y*32;
  #pragma unroll
  for(int i=0;i<32;i+=8)
    tile[ty+i][tx] = in[(size_t)(by+ty+i)*C + bx + tx];
  __syncthreads();
  #pragma unroll
  for(int i=0;i<32;i+=8){
    const float v = tile[tx][ty+i];
    u16 h, l; split2(v, h, l);
    const size_t o = (size_t)(bx+ty+i)*R + by + tx;
    outh[o] = h; outl[o] = l;
  }
}
__global__ __launch_bounds__(256)
void transpose_plain(const float* __restrict__ in, u16* __restrict__ outh, int R, int C)
{
  __shared__ float tile[32][33];
  const int tx = threadIdx.x & 31, ty = threadIdx.x >> 5;
  const int bx = blockIdx.x*32, by = blockIdx.y*32;
  #pragma unroll
  for(int i=0;i<32;i+=8)
    tile[ty+i][tx] = in[(size_t)(by+ty+i)*C + bx + tx];
  __syncthreads();
  #pragma unroll
  for(int i=0;i<32;i+=8)
    outh[(size_t)(bx+ty+i)*R + by + tx] = f2bf(tile[tx][ty+i]);
}
// fp32 -> split-bf16, no transpose (for raw Wq used in the Gt trick)
__global__ __launch_bounds__(256)
void split_convert(const float* __restrict__ in, u16* __restrict__ oh,
                   u16* __restrict__ ol)
{
  const int i = blockIdx.x*256 + threadIdx.x;
  const float4 v = ((const float4*)in)[i];
  ushort4 h4, l4;
  split2(v.x, h4.x, l4.x); split2(v.y, h4.y, l4.y);
  split2(v.z, h4.z, l4.z); split2(v.w, h4.w, l4.w);
  ((ushort4*)oh)[i] = h4; ((ushort4*)ol)[i] = l4;
}

// ============================================================================
// LayerNorm D=1024 fp32 in -> split-bf16 out
// ============================================================================
__global__ __launch_bounds__(256)
void layernorm_rows(const float* __restrict__ in, const float* __restrict__ g,
                    const float* __restrict__ bb, u16* __restrict__ outh,
                    u16* __restrict__ outl, int ostride)
{
  __shared__ float buf[4];
  const int row = blockIdx.x, tid = threadIdx.x;
  const float4 xv = ((const float4*)(in + (size_t)row*1024))[tid];
  float s  = bredsum(xv.x+xv.y+xv.z+xv.w, buf, tid);
  float s2 = bredsum(xv.x*xv.x+xv.y*xv.y+xv.z*xv.z+xv.w*xv.w, buf, tid);
  const float mean = s * (1.f/1024.f);
  const float var  = s2 * (1.f/1024.f) - mean*mean;
  const float rs   = 1.f / sqrtf(var + 1e-5f);
  const float4 gv = ((const float4*)g)[tid];
  const float4 bv = ((const float4*)bb)[tid];
  float o0 = (xv.x-mean)*rs*gv.x + bv.x;
  float o1 = (xv.y-mean)*rs*gv.y + bv.y;
  float o2 = (xv.z-mean)*rs*gv.z + bv.z;
  float o3 = (xv.w-mean)*rs*gv.w + bv.w;
  ushort4 oh, ol;
  split2(o0, oh.x, ol.x); split2(o1, oh.y, ol.y);
  split2(o2, oh.z, ol.z); split2(o3, oh.w, ol.w);
  ((ushort4*)(outh + (size_t)row*ostride))[tid] = oh;
  ((ushort4*)(outl + (size_t)row*ostride))[tid] = ol;
}

__global__ __launch_bounds__(256)
void edges_ln(const float* __restrict__ noise, const float* __restrict__ mu,
              const float* __restrict__ lsig, const float* __restrict__ g,
              const float* __restrict__ bb, u16* __restrict__ outh,
              u16* __restrict__ outl, int ostride)
{
  __shared__ float buf[4];
  const int row = blockIdx.x, tid = threadIdx.x;
  const float4 nv  = ((const float4*)(noise + (size_t)row*1024))[tid];
  const float4 muv = ((const float4*)mu)[tid];
  const float4 lsv = ((const float4*)lsig)[tid];
  float v0 = muv.x + expf(lsv.x)*nv.x;
  float v1 = muv.y + expf(lsv.y)*nv.y;
  float v2 = muv.z + expf(lsv.z)*nv.z;
  float v3 = muv.w + expf(lsv.w)*nv.w;
  float s  = bredsum(v0+v1+v2+v3, buf, tid);
  float s2 = bredsum(v0*v0+v1*v1+v2*v2+v3*v3, buf, tid);
  const float mean = s * (1.f/1024.f);
  const float var  = s2 * (1.f/1024.f) - mean*mean;
  const float rs   = 1.f / sqrtf(var + 1e-5f);
  const float4 gv = ((const float4*)g)[tid];
  const float4 bv = ((const float4*)bb)[tid];
  float o0 = (v0-mean)*rs*gv.x + bv.x;
  float o1 = (v1-mean)*rs*gv.y + bv.y;
  float o2 = (v2-mean)*rs*gv.z + bv.z;
  float o3 = (v3-mean)*rs*gv.w + bv.w;
  ushort4 oh, ol;
  split2(o0, oh.x, ol.x); split2(o1, oh.y, ol.y);
  split2(o2, oh.z, ol.z); split2(o3, oh.w, ol.w);
  ((ushort4*)(outh + (size_t)row*ostride))[tid] = oh;
  ((ushort4*)(outl + (size_t)row*ostride))[tid] = ol;
}

// ============================================================================
// softmax(8192)+eps+renorm + top-k_n -> (idx, weight) pairs. 1 block/row.
// ============================================================================
#define USI(i) ((i) + ((i)>>5))
__global__ __launch_bounds__(256)
void softmax_topk_a(const float* __restrict__ dots, const int* __restrict__ knp,
                    int* __restrict__ tidx, float* __restrict__ tw)
{
  const int NC = 8192;
  __shared__ uint32_t us[8192 + 256];
  __shared__ float fbuf[4];
  __shared__ int ibuf[4];
  __shared__ int scan[256];
  __shared__ int slot_ctr;
  const int row = blockIdx.x, tid = threadIdx.x;
  const float* x = dots + (size_t)row * NC;

  float mx = -3.4e38f;
  for(int i=tid;i<NC;i+=256){ float f = x[i]; us[USI(i)] = fmap(f); mx = fmaxf(mx, f); }
  mx = bredmax(mx, fbuf, tid);
  float se = 0.f;
  for(int i=tid;i<NC;i+=256) se += expf(funmap(us[USI(i)]) - mx);
  se = bredsum(se, fbuf, tid);
  float ts = 0.f;
  for(int i=tid;i<NC;i+=256) ts += expf(funmap(us[USI(i)]) - mx)/se + 1e-8f;
  const float T = bredsum(ts, fbuf, tid);

  const int k = knp[0];
  uint32_t lo = 0u, hi = 0xFFFFFFFFu;
  const int base = tid*32;
  while(lo < hi){
    const uint32_t mid = lo + ((hi - lo) >> 1) + 1u;
    int c = 0;
    #pragma unroll 8
    for(int j=0;j<32;j++) c += (us[USI(base+j)] >= mid);
    c = bredsumi(c, ibuf, tid);
    if(c >= k) lo = mid; else hi = mid - 1u;
  }
  const uint32_t uth = lo;
  int gt = 0, eq = 0;
  #pragma unroll 8
  for(int j=0;j<32;j++){ uint32_t u = us[USI(base+j)]; gt += (u>uth); eq += (u==uth); }
  const int c1 = bredsumi(gt, ibuf, tid);
  __syncthreads();
  scan[tid] = eq;
  __syncthreads();
  #pragma unroll
  for(int o=1;o<256;o<<=1){
    int t = (tid>=o) ? scan[tid-o] : 0;
    __syncthreads();
    scan[tid] += t;
    __syncthreads();
  }
  int eq_rank = scan[tid] - eq;
  const int budget = k - c1;
  if(tid==0) slot_ctr = 0;
  __syncthreads();
  for(int j=0;j<32;j++){
    const int i = base + j;
    const uint32_t u = us[USI(i)];
    bool sel = (u > uth);
    if(u == uth){ sel = (eq_rank < budget); eq_rank++; }
    if(sel){
      const int s = atomicAdd(&slot_ctr, 1);
      const float f = funmap(u);
      const float w = (expf(f - mx)/se + 1e-8f) / T;
      if(s < 128){ tidx[row*128 + s] = i; tw[row*128 + s] = w; }
    }
  }
}

// updates[row] = sum_j w_j * v[idx_j] (v bf16) ; split-bf16 into cat[:,1024:]
__global__ __launch_bounds__(256)
void gather_updates(const int* __restrict__ tidx, const float* __restrict__ tw,
                    const int* __restrict__ knp, const u16* __restrict__ v,
                    u16* __restrict__ cath, u16* __restrict__ catl)
{
  __shared__ int   idx_s[128];
  __shared__ float w_s[128];
  const int row = blockIdx.x, tid = threadIdx.x;
  const int kk = knp[0];
  if(tid < 128){
    idx_s[tid] = (tid < kk) ? (tidx[row*128+tid] & 8191) : 0;
    w_s[tid]   = (tid < kk) ? tw[row*128+tid] : 0.f;
  }
  __syncthreads();
  const int c = tid*4;
  float a0=0,a1=0,a2=0,a3=0;
  for(int j=0;j<kk && j<128;j++){
    const ushort4 vv = *(const ushort4*)&v[(size_t)idx_s[j]*1024 + c];
    const float w = w_s[j];
    a0 += w*bf2f(vv.x); a1 += w*bf2f(vv.y); a2 += w*bf2f(vv.z); a3 += w*bf2f(vv.w);
  }
  ushort4 oh, ol;
  split2(a0, oh.x, ol.x); split2(a1, oh.y, ol.y);
  split2(a2, oh.z, ol.z); split2(a3, oh.w, ol.w);
  ((ushort4*)(cath + (size_t)row*2048 + 1024))[tid] = oh;
  ((ushort4*)(catl + (size_t)row*2048 + 1024))[tid] = ol;
}

// bias_v[m] = dot(bq, k2[m]) / 32   (k2 = split-bf16)
__global__ __launch_bounds__(256)
void bias_v_kernel(const float* __restrict__ bq, const u16* __restrict__ k2h,
                   const u16* __restrict__ k2l, float* __restrict__ out)
{
  __shared__ float buf[4];
  const int row = blockIdx.x, tid = threadIdx.x;
  const ushort4 h4 = ((const ushort4*)(k2h + (size_t)row*1024))[tid];
  const ushort4 l4 = ((const ushort4*)(k2l + (size_t)row*1024))[tid];
  const float4 b4 = ((const float4*)bq)[tid];
  float s = b4.x*(bf2f(h4.x)+bf2f(l4.x)) + b4.y*(bf2f(h4.y)+bf2f(l4.y))
          + b4.z*(bf2f(h4.z)+bf2f(l4.z)) + b4.w*(bf2f(h4.w)+bf2f(l4.w));
  s = bredsum(s, buf, tid);
  if(tid==0) out[row] = s * 0.03125f;
}

// ============================================================================
// H: softmax over 512 + top-k_e mask, one WAVE per row (4 rows/block).
// No LDS, no barriers: 8 elems/lane in registers, shfl butterflies,
// iterative argmax extraction (tie -> lowest index == JAX top_k set).
// ============================================================================
__global__ __launch_bounds__(256)
void softmax_topk_h_wave(const float* __restrict__ dv, const int* __restrict__ kep,
                         float* __restrict__ H)
{
  const int wave = threadIdx.x >> 6, lane = threadIdx.x & 63;
  const int row = blockIdx.x*4 + wave;
  const float* x = dv + (size_t)row*512 + lane*8;
  const float4 a = *(const float4*)x;
  const float4 b = *(const float4*)(x+4);
  float vals[8] = {a.x,a.y,a.z,a.w,b.x,b.y,b.z,b.w};

  // wave max
  float mx = vals[0];
  #pragma unroll
  for(int j=1;j<8;j++) mx = fmaxf(mx, vals[j]);
  #pragma unroll
  for(int o=32;o;o>>=1) mx = fmaxf(mx, __shfl_xor(mx, o));
  // wave sum of exp
  float e[8], se = 0.f;
  #pragma unroll
  for(int j=0;j<8;j++){ e[j] = expf(vals[j]-mx); se += e[j]; }
  #pragma unroll
  for(int o=32;o;o>>=1) se += __shfl_xor(se, o);
  const float inv = 1.f/se;

  // iterative top-k extraction on packed keys: (fmap(v)<<9) | (511-idx)
  const int k = kep[0];
  unsigned int selmask = 0;
  for(int r=0;r<k;r++){
    unsigned long long best = 0;
    #pragma unroll
    for(int j=0;j<8;j++){
      if(!((selmask>>j)&1u)){
        const unsigned long long key =
          ((unsigned long long)fmap(vals[j]) << 9) | (unsigned long long)(511 - (lane*8+j));
        if(key > best) best = key;
      }
    }
    #pragma unroll
    for(int o=32;o;o>>=1){
      const unsigned long long other = __shfl_xor(best, o);
      if(other > best) best = other;
    }
    const int bidx = 511 - (int)(best & 511ull);
    if((bidx>>3) == lane) selmask |= 1u << (bidx & 7);
  }

  float4 o0, o1;
  o0.x = (selmask&  1u) ? e[0]*inv : 0.f;
  o0.y = (selmask&  2u) ? e[1]*inv : 0.f;
  o0.z = (selmask&  4u) ? e[2]*inv : 0.f;
  o0.w = (selmask&  8u) ? e[3]*inv : 0.f;
  o1.x = (selmask& 16u) ? e[4]*inv : 0.f;
  o1.y = (selmask& 32u) ? e[5]*inv : 0.f;
  o1.z = (selmask& 64u) ? e[6]*inv : 0.f;
  o1.w = (selmask&128u) ? e[7]*inv : 0.f;
  float* outp = H + (size_t)row*512 + lane*8;
  *(float4*)outp     = o0;
  *(float4*)(outp+4) = o1;
}

// ============================================================================
extern "C" void kernel_launch(void* const* d_in, const int* in_sizes, int n_in,
                              void* d_out, int out_size, void* d_ws, size_t ws_size,
                              hipStream_t stream)
{
  const float* inputs = (const float*)d_in[0];
  const float* noise  = (const float*)d_in[1];
  const float* emu    = (const float*)d_in[2];
  const float* elsig  = (const float*)d_in[3];
  const float* Wq = (const float*)d_in[4];  const float* bq = (const float*)d_in[5];
  const float* Wk = (const float*)d_in[6];  const float* bk = (const float*)d_in[7];
  const float* Wv = (const float*)d_in[8];  const float* bv = (const float*)d_in[9];
  const float* W1 = (const float*)d_in[10]; const float* b1 = (const float*)d_in[11];
  const float* W2 = (const float*)d_in[12]; const float* b2 = (const float*)d_in[13];
  const float* g_in = (const float*)d_in[14]; const float* b_in = (const float*)d_in[15];
  const float* g_e  = (const float*)d_in[16]; const float* b_e  = (const float*)d_in[17];
  const int* knp = (const int*)d_in[18];
  const int* kep = (const int*)d_in[19];

  float* out = (float*)d_out;
  float* out_edges = out;                             // 512*1024
  float* out_H     = out + 512*1024;                  // 8192*512
  float* out_dots  = out + 512*1024 + 8192*512;       // 512*8192

  // ---- workspace (~102 MB peak, stream-ordered reuse) ----
  char* p = (char*)d_ws;
  const size_t MB = 1024ull*1024;
  u16* xh = (u16*)(p + 0*MB);            // x split, live to the end (dots_v)
  u16* xl = (u16*)(p + 16*MB);
  u16* kb = (u16*)(p + 32*MB);           // k bf16, dead after dots GEMM
  u16* vb = (u16*)(p + 48*MB);           // v bf16, dead after gather
  float* dotsvf = (float*)(p + 32*MB);   // dots_v fp32 (reuses kb region)
  // weights [64,88)
  u16* WkTh = (u16*)(p + 64*MB);  u16* WkTl = (u16*)(p + 66*MB);
  u16* WvTh = (u16*)(p + 68*MB);
  u16* WqTh = (u16*)(p + 70*MB);
  u16* Wqh  = (u16*)(p + 72*MB);  u16* Wql  = (u16*)(p + 74*MB);   // raw (no T)
  u16* W1Th = (u16*)(p + 76*MB);  u16* W1Tl = (u16*)(p + 80*MB);
  u16* W2Th = (u16*)(p + 84*MB);  u16* W2Tl = (u16*)(p + 86*MB);
  // small [88,102)
  u16* cath = (u16*)(p + 88*MB);  u16* catl = (u16*)(p + 90*MB);
  u16* qmb  = (u16*)(p + 92*MB);
  u16* h1h  = (u16*)(p + 93*MB);  u16* h1l  = (u16*)(p + 94*MB);
  u16* eoh  = (u16*)(p + 95*MB);  u16* eol  = (u16*)(p + 96*MB);
  u16* k2h  = (u16*)(p + 97*MB);  u16* k2l  = (u16*)(p + 98*MB);
  u16* Gth  = (u16*)(p + 99*MB);  u16* Gtl  = (u16*)(p + 100*MB);
  int*   tidx  = (int*)  (p + 101*MB);
  float* tw    = (float*)(p + 101*MB + 256*1024);
  float* biasv = (float*)(p + 101*MB + 512*1024);

  hipMemsetAsync(tidx, 0, 512ull*128*4, stream);
  hipMemsetAsync(tw,   0, 512ull*128*4, stream);

  // weight prep
  transpose_split<<<dim3(32,32),256,0,stream>>>(Wk, WkTh, WkTl, 1024, 1024);
  transpose_split<<<dim3(32,64),256,0,stream>>>(W1, W1Th, W1Tl, 2048, 1024);
  transpose_split<<<dim3(32,32),256,0,stream>>>(W2, W2Th, W2Tl, 1024, 1024);
  transpose_plain<<<dim3(32,32),256,0,stream>>>(Wv, WvTh, 1024, 1024);
  transpose_plain<<<dim3(32,32),256,0,stream>>>(Wq, WqTh, 1024, 1024);
  split_convert<<<1024,256,0,stream>>>(Wq, Wqh, Wql);

  layernorm_rows<<<8192,256,0,stream>>>(inputs, g_in, b_in, xh, xl, 1024);
  edges_ln<<<512,256,0,stream>>>(noise, emu, elsig, g_e, b_e, cath, catl, 2048);

  // --- dots chain (plain bf16; selection-tolerant) ---
  gemm1<true ><<<dim3(8,64),256,0,stream>>>(xh,1024, WkTh,1024, bk, 1.f,
                                            kb,nullptr, 1024,1024);
  gemm1<true ><<<dim3(8,64),256,0,stream>>>(xh,1024, WvTh,1024, bv, 1.f,
                                            vb,nullptr, 1024,1024);
  gemm1<true ><<<dim3(8,4),256,0,stream>>>(cath,2048, WqTh,1024, bq, 1.f,
                                           qmb,nullptr, 1024,1024);
  gemm1<false><<<dim3(64,4),256,0,stream>>>(qmb,1024, kb,1024, nullptr, 0.03125f,
                                            nullptr,out_dots, 1024,8192);
  softmax_topk_a<<<512,256,0,stream>>>(out_dots, knp, tidx, tw);
  gather_updates<<<512,256,0,stream>>>(tidx, tw, knp, vb, cath, catl);

  // --- edges + H chain (split-bf16, fp32-class) ---
  gemm3<true ><<<dim3(8,4),256,0,stream>>>(cath,catl,2048, W1Th,W1Tl,2048, b1, 1.f,
                                           h1h,h1l, nullptr, 2048,1024);
  gemm3<false><<<dim3(8,4),256,0,stream>>>(h1h,h1l,1024, W2Th,W2Tl,1024, b2, 1.f,
                                           eoh,eol, out_edges, 1024,1024);
  gemm3<true ><<<dim3(8,4),256,0,stream>>>(eoh,eol,1024, WkTh,WkTl,1024, bk, 1.f,
                                           k2h,k2l, nullptr, 1024,1024);
  // Gt[m,e] = sum_d k2[m,d] * Wq[e,d]  (associativity: dots_v = x@Gt^T/32 + bias)
  gemm3<false><<<dim3(8,4),256,0,stream>>>(k2h,k2l,1024, Wqh,Wql,1024, nullptr, 1.f,
                                           Gth,Gtl, nullptr, 1024,1024);
  bias_v_kernel<<<512,256,0,stream>>>(bq, k2h, k2l, biasv);
  gemm3<false><<<dim3(4,64),256,0,stream>>>(xh,xl,1024, Gth,Gtl,1024, biasv, 0.03125f,
                                            nullptr,nullptr, dotsvf, 1024,512);
  softmax_topk_h_wave<<<2048,256,0,stream>>>(dotsvf, kep, out_H);
}

// Round 8
// 431.076 us; speedup vs baseline: 3.5077x; 1.2783x over previous
//
#include <hip/hip_runtime.h>
#include <stdint.h>
#include <stddef.h>

typedef unsigned short u16;
typedef __bf16 bf16x8 __attribute__((ext_vector_type(8)));
typedef float f32x4 __attribute__((ext_vector_type(4)));

#define DEV __device__ __forceinline__

DEV float bf2f(u16 u){ union{uint32_t i; float f;} c; c.i=(uint32_t)u<<16; return c.f; }
DEV u16 f2bf(float f){ union{float f; uint32_t i;} c; c.f=f; uint32_t x=c.i;
  uint32_t r = x + 0x7FFFu + ((x>>16)&1u); return (u16)(r>>16); }
DEV uint32_t fmap(float f){ union{float f; uint32_t u;} c; c.f=f;
  return (c.u & 0x80000000u) ? ~c.u : (c.u | 0x80000000u); }
DEV float funmap(uint32_t u){ union{uint32_t u; float f;} c;
  c.u = (u & 0x80000000u) ? (u & 0x7FFFFFFFu) : ~u; return c.f; }
DEV void split2(float x, u16& h, u16& l){ h = f2bf(x); l = f2bf(x - bf2f(h)); }

// ---- block reductions (256 threads = 4 waves) ----
DEV float bredsum(float v, float* buf, int tid){
  #pragma unroll
  for(int o=32;o;o>>=1) v += __shfl_down(v,o);
  __syncthreads();
  if((tid&63)==0) buf[tid>>6]=v;
  __syncthreads();
  return buf[0]+buf[1]+buf[2]+buf[3];
}
DEV float bredmax(float v, float* buf, int tid){
  #pragma unroll
  for(int o=32;o;o>>=1) v = fmaxf(v, __shfl_down(v,o));
  __syncthreads();
  if((tid&63)==0) buf[tid>>6]=v;
  __syncthreads();
  return fmaxf(fmaxf(buf[0],buf[1]),fmaxf(buf[2],buf[3]));
}
DEV int bredsumi(int v, int* buf, int tid){
  #pragma unroll
  for(int o=32;o;o>>=1) v += __shfl_down(v,o);
  __syncthreads();
  if((tid&63)==0) buf[tid>>6]=v;
  __syncthreads();
  return buf[0]+buf[1]+buf[2]+buf[3];
}

// ============================================================================
// 64x128-tile plain bf16 GEMM. 4 waves: wave = 32(M)x64(N), acc[2][4].
// SK>1: K sliced by blockIdx.z, fp32 partials (no bias/act).
// SK==1: full epilogue (scale, bias, act, bf16/fp32 writes).
// ============================================================================
template<bool RELU, int SK>
__global__ __launch_bounds__(256)
void gemm1_64(const u16* __restrict__ A, int lda,
              const u16* __restrict__ Bt, int ldb,
              const float* __restrict__ bias, float scale,
              u16* __restrict__ outb, float* __restrict__ outf,
              float* __restrict__ part,
              int K, int ldc, int M)
{
  __shared__ __align__(16) u16 As[64*32];
  __shared__ __align__(16) u16 Bs[128*32];
  const int tid = threadIdx.x, lane = tid&63, wave = tid>>6;
  const int m0 = blockIdx.y*64, n0 = blockIdx.x*128;
  const int wm = (wave>>1)*32, wn = (wave&1)*64;
  const int ml = lane&15, quad = lane>>4;
  const int ks = K / SK;
  const int kbeg = blockIdx.z * ks;
  const u16* pa  = A  + (size_t)(m0+(tid>>2))*lda + kbeg + (tid&3)*8;
  const u16* pb0 = Bt + (size_t)(n0+(tid>>2))*ldb + kbeg + (tid&3)*8;
  const u16* pb1 = Bt + (size_t)(n0+64+(tid>>2))*ldb + kbeg + (tid&3)*8;

  f32x4 acc[2][4];
  #pragma unroll
  for(int i=0;i<2;i++)
    #pragma unroll
    for(int j=0;j<4;j++) acc[i][j] = (f32x4){0.f,0.f,0.f,0.f};

  uint4 ra=*(const uint4*)pa, rb0=*(const uint4*)pb0, rb1=*(const uint4*)pb1;
  for(int k0=0;k0<ks;k0+=32){
    __syncthreads();
    *(uint4*)&As[tid*8]       = ra;
    *(uint4*)&Bs[tid*8]       = rb0;
    *(uint4*)&Bs[(256+tid)*8] = rb1;
    __syncthreads();
    if(k0+32<ks){
      ra  = *(const uint4*)(pa +k0+32);
      rb0 = *(const uint4*)(pb0+k0+32);
      rb1 = *(const uint4*)(pb1+k0+32);
    }
    bf16x8 af[2], bf[4];
    #pragma unroll
    for(int mi=0;mi<2;mi++) af[mi] = *(const bf16x8*)&As[(wm+mi*16+ml)*32 + quad*8];
    #pragma unroll
    for(int ni=0;ni<4;ni++) bf[ni] = *(const bf16x8*)&Bs[(wn+ni*16+ml)*32 + quad*8];
    #pragma unroll
    for(int mi=0;mi<2;mi++)
      #pragma unroll
      for(int ni=0;ni<4;ni++)
        acc[mi][ni] = __builtin_amdgcn_mfma_f32_16x16x32_bf16(af[mi], bf[ni], acc[mi][ni], 0,0,0);
  }
  // C/D: col = lane&15, row = quad*4 + reg  (m89-verified)
  #pragma unroll
  for(int mi=0;mi<2;mi++){
    const int rbase = m0 + wm + mi*16 + quad*4;
    #pragma unroll
    for(int ni=0;ni<4;ni++){
      const int col = n0 + wn + ni*16 + ml;
      if(SK==1){
        const float bv = bias ? bias[col] : 0.f;
        #pragma unroll
        for(int r=0;r<4;r++){
          float v = acc[mi][ni][r]*scale + bv;
          if(RELU) v = fmaxf(v, 0.f);
          const size_t idx = (size_t)(rbase + r)*ldc + col;
          if(outb) outb[idx] = f2bf(v);
          if(outf) outf[idx] = v;
        }
      }else{
        #pragma unroll
        for(int r=0;r<4;r++)
          part[((size_t)blockIdx.z*M + rbase + r)*ldc + col] = acc[mi][ni][r];
      }
    }
  }
}

// ============================================================================
// 64x128-tile split-bf16 GEMM (fp32-class, 3 MFMAs/step). Same SK scheme.
// ============================================================================
template<bool RELU, int SK>
__global__ __launch_bounds__(256)
void gemm3_64(const u16* __restrict__ Ah, const u16* __restrict__ Al, int lda,
              const u16* __restrict__ Bh, const u16* __restrict__ Bl, int ldb,
              const float* __restrict__ bias, float scale,
              u16* __restrict__ outh, u16* __restrict__ outl,
              float* __restrict__ outf, float* __restrict__ part,
              int K, int ldc, int M)
{
  __shared__ __align__(16) u16 AsH[64*32];
  __shared__ __align__(16) u16 AsL[64*32];
  __shared__ __align__(16) u16 BsH[128*32];
  __shared__ __align__(16) u16 BsL[128*32];
  const int tid = threadIdx.x, lane = tid&63, wave = tid>>6;
  const int m0 = blockIdx.y*64, n0 = blockIdx.x*128;
  const int wm = (wave>>1)*32, wn = (wave&1)*64;
  const int ml = lane&15, quad = lane>>4;
  const int ks = K / SK;
  const int kbeg = blockIdx.z * ks;
  const size_t ao  = (size_t)(m0+(tid>>2))*lda + kbeg + (tid&3)*8;
  const size_t bo0 = (size_t)(n0+(tid>>2))*ldb + kbeg + (tid&3)*8;
  const size_t bo1 = (size_t)(n0+64+(tid>>2))*ldb + kbeg + (tid&3)*8;

  f32x4 acc[2][4];
  #pragma unroll
  for(int i=0;i<2;i++)
    #pragma unroll
    for(int j=0;j<4;j++) acc[i][j] = (f32x4){0.f,0.f,0.f,0.f};

  uint4 rah=*(const uint4*)(Ah+ao),  ral=*(const uint4*)(Al+ao);
  uint4 rbh0=*(const uint4*)(Bh+bo0), rbl0=*(const uint4*)(Bl+bo0);
  uint4 rbh1=*(const uint4*)(Bh+bo1), rbl1=*(const uint4*)(Bl+bo1);
  for(int k0=0;k0<ks;k0+=32){
    __syncthreads();
    *(uint4*)&AsH[tid*8]       = rah;
    *(uint4*)&AsL[tid*8]       = ral;
    *(uint4*)&BsH[tid*8]       = rbh0;
    *(uint4*)&BsL[tid*8]       = rbl0;
    *(uint4*)&BsH[(256+tid)*8] = rbh1;
    *(uint4*)&BsL[(256+tid)*8] = rbl1;
    __syncthreads();
    if(k0+32<ks){
      const int s = k0+32;
      rah =*(const uint4*)(Ah+ao +s); ral =*(const uint4*)(Al+ao +s);
      rbh0=*(const uint4*)(Bh+bo0+s); rbl0=*(const uint4*)(Bl+bo0+s);
      rbh1=*(const uint4*)(Bh+bo1+s); rbl1=*(const uint4*)(Bl+bo1+s);
    }
    bf16x8 afh[2], afl[2], bfh[4], bfl[4];
    #pragma unroll
    for(int mi=0;mi<2;mi++){
      const int o = (wm+mi*16+ml)*32 + quad*8;
      afh[mi] = *(const bf16x8*)&AsH[o];
      afl[mi] = *(const bf16x8*)&AsL[o];
    }
    #pragma unroll
    for(int ni=0;ni<4;ni++){
      const int o = (wn+ni*16+ml)*32 + quad*8;
      bfh[ni] = *(const bf16x8*)&BsH[o];
      bfl[ni] = *(const bf16x8*)&BsL[o];
    }
    #pragma unroll
    for(int mi=0;mi<2;mi++)
      #pragma unroll
      for(int ni=0;ni<4;ni++){
        acc[mi][ni] = __builtin_amdgcn_mfma_f32_16x16x32_bf16(afh[mi], bfh[ni], acc[mi][ni], 0,0,0);
        acc[mi][ni] = __builtin_amdgcn_mfma_f32_16x16x32_bf16(afh[mi], bfl[ni], acc[mi][ni], 0,0,0);
        acc[mi][ni] = __builtin_amdgcn_mfma_f32_16x16x32_bf16(afl[mi], bfh[ni], acc[mi][ni], 0,0,0);
      }
  }
  #pragma unroll
  for(int mi=0;mi<2;mi++){
    const int rbase = m0 + wm + mi*16 + quad*4;
    #pragma unroll
    for(int ni=0;ni<4;ni++){
      const int col = n0 + wn + ni*16 + ml;
      if(SK==1){
        const float bv = bias ? bias[col] : 0.f;
        #pragma unroll
        for(int r=0;r<4;r++){
          float v = acc[mi][ni][r]*scale + bv;
          if(RELU) v = fmaxf(v, 0.f);
          const size_t idx = (size_t)(rbase + r)*ldc + col;
          if(outh){ u16 h, l; split2(v, h, l); outh[idx] = h; outl[idx] = l; }
          if(outf) outf[idx] = v;
        }
      }else{
        #pragma unroll
        for(int r=0;r<4;r++)
          part[((size_t)blockIdx.z*M + rbase + r)*ldc + col] = acc[mi][ni][r];
      }
    }
  }
}

// ============================================================================
// reduce SK fp32 partials + bias/act -> split-bf16 / bf16 / fp32 outputs.
// grid = MN/1024 blocks. N multiple of 4.
// ============================================================================
template<bool RELU, int SK>
__global__ __launch_bounds__(256)
void reduce_epi(const float* __restrict__ part, const float* __restrict__ bias,
                float scale, u16* __restrict__ outh, u16* __restrict__ outl,
                u16* __restrict__ outb, float* __restrict__ outf,
                size_t MN, int N)
{
  const size_t i = ((size_t)blockIdx.x*256 + threadIdx.x)*4;
  float4 s = *(const float4*)(part + i);
  #pragma unroll
  for(int z=1; z<SK; z++){
    const float4 t = *(const float4*)(part + (size_t)z*MN + i);
    s.x += t.x; s.y += t.y; s.z += t.z; s.w += t.w;
  }
  const int col = (int)(i % (size_t)N);
  float4 bv = bias ? *(const float4*)(bias + col) : (float4){0.f,0.f,0.f,0.f};
  float v[4] = { s.x*scale + bv.x, s.y*scale + bv.y, s.z*scale + bv.z, s.w*scale + bv.w };
  if(RELU){
    #pragma unroll
    for(int j=0;j<4;j++) v[j] = fmaxf(v[j], 0.f);
  }
  if(outh){
    ushort4 h4, l4;
    split2(v[0], h4.x, l4.x); split2(v[1], h4.y, l4.y);
    split2(v[2], h4.z, l4.z); split2(v[3], h4.w, l4.w);
    *(ushort4*)(outh + i) = h4;
    *(ushort4*)(outl + i) = l4;
  }
  if(outb){
    ushort4 b4;
    b4.x=f2bf(v[0]); b4.y=f2bf(v[1]); b4.z=f2bf(v[2]); b4.w=f2bf(v[3]);
    *(ushort4*)(outb + i) = b4;
  }
  if(outf) *(float4*)(outf + i) = (float4){v[0],v[1],v[2],v[3]};
}

// ============================================================================
// fp32 transpose -> split-bf16 / plain-bf16 ; fp32 -> split-bf16 convert
// ============================================================================
__global__ __launch_bounds__(256)
void transpose_split(const float* __restrict__ in, u16* __restrict__ outh,
                     u16* __restrict__ outl, int R, int C)
{
  __shared__ float tile[32][33];
  const int tx = threadIdx.x & 31, ty = threadIdx.x >> 5;
  const int bx = blockIdx.x*32, by = blockIdx.y*32;
  #pragma unroll
  for(int i=0;i<32;i+=8)
    tile[ty+i][tx] = in[(size_t)(by+ty+i)*C + bx + tx];
  __syncthreads();
  #pragma unroll
  for(int i=0;i<32;i+=8){
    const float v = tile[tx][ty+i];
    u16 h, l; split2(v, h, l);
    const size_t o = (size_t)(bx+ty+i)*R + by + tx;
    outh[o] = h; outl[o] = l;
  }
}
__global__ __launch_bounds__(256)
void transpose_plain(const float* __restrict__ in, u16* __restrict__ outh, int R, int C)
{
  __shared__ float tile[32][33];
  const int tx = threadIdx.x & 31, ty = threadIdx.x >> 5;
  const int bx = blockIdx.x*32, by = blockIdx.y*32;
  #pragma unroll
  for(int i=0;i<32;i+=8)
    tile[ty+i][tx] = in[(size_t)(by+ty+i)*C + bx + tx];
  __syncthreads();
  #pragma unroll
  for(int i=0;i<32;i+=8)
    outh[(size_t)(bx+ty+i)*R + by + tx] = f2bf(tile[tx][ty+i]);
}
__global__ __launch_bounds__(256)
void split_convert(const float* __restrict__ in, u16* __restrict__ oh,
                   u16* __restrict__ ol)
{
  const int i = blockIdx.x*256 + threadIdx.x;
  const float4 v = ((const float4*)in)[i];
  ushort4 h4, l4;
  split2(v.x, h4.x, l4.x); split2(v.y, h4.y, l4.y);
  split2(v.z, h4.z, l4.z); split2(v.w, h4.w, l4.w);
  ((ushort4*)oh)[i] = h4; ((ushort4*)ol)[i] = l4;
}

// ============================================================================
// LayerNorm D=1024 fp32 in -> split-bf16 out
// ============================================================================
__global__ __launch_bounds__(256)
void layernorm_rows(const float* __restrict__ in, const float* __restrict__ g,
                    const float* __restrict__ bb, u16* __restrict__ outh,
                    u16* __restrict__ outl, int ostride)
{
  __shared__ float buf[4];
  const int row = blockIdx.x, tid = threadIdx.x;
  const float4 xv = ((const float4*)(in + (size_t)row*1024))[tid];
  float s  = bredsum(xv.x+xv.y+xv.z+xv.w, buf, tid);
  float s2 = bredsum(xv.x*xv.x+xv.y*xv.y+xv.z*xv.z+xv.w*xv.w, buf, tid);
  const float mean = s * (1.f/1024.f);
  const float var  = s2 * (1.f/1024.f) - mean*mean;
  const float rs   = 1.f / sqrtf(var + 1e-5f);
  const float4 gv = ((const float4*)g)[tid];
  const float4 bv = ((const float4*)bb)[tid];
  float o0 = (xv.x-mean)*rs*gv.x + bv.x;
  float o1 = (xv.y-mean)*rs*gv.y + bv.y;
  float o2 = (xv.z-mean)*rs*gv.z + bv.z;
  float o3 = (xv.w-mean)*rs*gv.w + bv.w;
  ushort4 oh, ol;
  split2(o0, oh.x, ol.x); split2(o1, oh.y, ol.y);
  split2(o2, oh.z, ol.z); split2(o3, oh.w, ol.w);
  ((ushort4*)(outh + (size_t)row*ostride))[tid] = oh;
  ((ushort4*)(outl + (size_t)row*ostride))[tid] = ol;
}

__global__ __launch_bounds__(256)
void edges_ln(const float* __restrict__ noise, const float* __restrict__ mu,
              const float* __restrict__ lsig, const float* __restrict__ g,
              const float* __restrict__ bb, u16* __restrict__ outh,
              u16* __restrict__ outl, int ostride)
{
  __shared__ float buf[4];
  const int row = blockIdx.x, tid = threadIdx.x;
  const float4 nv  = ((const float4*)(noise + (size_t)row*1024))[tid];
  const float4 muv = ((const float4*)mu)[tid];
  const float4 lsv = ((const float4*)lsig)[tid];
  float v0 = muv.x + expf(lsv.x)*nv.x;
  float v1 = muv.y + expf(lsv.y)*nv.y;
  float v2 = muv.z + expf(lsv.z)*nv.z;
  float v3 = muv.w + expf(lsv.w)*nv.w;
  float s  = bredsum(v0+v1+v2+v3, buf, tid);
  float s2 = bredsum(v0*v0+v1*v1+v2*v2+v3*v3, buf, tid);
  const float mean = s * (1.f/1024.f);
  const float var  = s2 * (1.f/1024.f) - mean*mean;
  const float rs   = 1.f / sqrtf(var + 1e-5f);
  const float4 gv = ((const float4*)g)[tid];
  const float4 bv = ((const float4*)bb)[tid];
  float o0 = (v0-mean)*rs*gv.x + bv.x;
  float o1 = (v1-mean)*rs*gv.y + bv.y;
  float o2 = (v2-mean)*rs*gv.z + bv.z;
  float o3 = (v3-mean)*rs*gv.w + bv.w;
  ushort4 oh, ol;
  split2(o0, oh.x, ol.x); split2(o1, oh.y, ol.y);
  split2(o2, oh.z, ol.z); split2(o3, oh.w, ol.w);
  ((ushort4*)(outh + (size_t)row*ostride))[tid] = oh;
  ((ushort4*)(outl + (size_t)row*ostride))[tid] = ol;
}

// ============================================================================
// softmax(8192)+eps+renorm + top-k_n -> (idx, weight) pairs. 1 block/row.
// ============================================================================
#define USI(i) ((i) + ((i)>>5))
__global__ __launch_bounds__(256)
void softmax_topk_a(const float* __restrict__ dots, const int* __restrict__ knp,
                    int* __restrict__ tidx, float* __restrict__ tw)
{
  const int NC = 8192;
  __shared__ uint32_t us[8192 + 256];
  __shared__ float fbuf[4];
  __shared__ int ibuf[4];
  __shared__ int scan[256];
  __shared__ int slot_ctr;
  const int row = blockIdx.x, tid = threadIdx.x;
  const float* x = dots + (size_t)row * NC;

  float mx = -3.4e38f;
  for(int i=tid;i<NC;i+=256){ float f = x[i]; us[USI(i)] = fmap(f); mx = fmaxf(mx, f); }
  mx = bredmax(mx, fbuf, tid);
  float se = 0.f;
  for(int i=tid;i<NC;i+=256) se += expf(funmap(us[USI(i)]) - mx);
  se = bredsum(se, fbuf, tid);
  float ts = 0.f;
  for(int i=tid;i<NC;i+=256) ts += expf(funmap(us[USI(i)]) - mx)/se + 1e-8f;
  const float T = bredsum(ts, fbuf, tid);

  const int k = knp[0];
  uint32_t lo = 0u, hi = 0xFFFFFFFFu;
  const int base = tid*32;
  while(lo < hi){
    const uint32_t mid = lo + ((hi - lo) >> 1) + 1u;
    int c = 0;
    #pragma unroll 8
    for(int j=0;j<32;j++) c += (us[USI(base+j)] >= mid);
    c = bredsumi(c, ibuf, tid);
    if(c >= k) lo = mid; else hi = mid - 1u;
  }
  const uint32_t uth = lo;
  int gt = 0, eq = 0;
  #pragma unroll 8
  for(int j=0;j<32;j++){ uint32_t u = us[USI(base+j)]; gt += (u>uth); eq += (u==uth); }
  const int c1 = bredsumi(gt, ibuf, tid);
  __syncthreads();
  scan[tid] = eq;
  __syncthreads();
  #pragma unroll
  for(int o=1;o<256;o<<=1){
    int t = (tid>=o) ? scan[tid-o] : 0;
    __syncthreads();
    scan[tid] += t;
    __syncthreads();
  }
  int eq_rank = scan[tid] - eq;
  const int budget = k - c1;
  if(tid==0) slot_ctr = 0;
  __syncthreads();
  for(int j=0;j<32;j++){
    const int i = base + j;
    const uint32_t u = us[USI(i)];
    bool sel = (u > uth);
    if(u == uth){ sel = (eq_rank < budget); eq_rank++; }
    if(sel){
      const int s = atomicAdd(&slot_ctr, 1);
      const float f = funmap(u);
      const float w = (expf(f - mx)/se + 1e-8f) / T;
      if(s < 128){ tidx[row*128 + s] = i; tw[row*128 + s] = w; }
    }
  }
}

// updates[row] = sum_j w_j * v[idx_j] (v bf16) ; split-bf16 into cat[:,1024:]
__global__ __launch_bounds__(256)
void gather_updates(const int* __restrict__ tidx, const float* __restrict__ tw,
                    const int* __restrict__ knp, const u16* __restrict__ v,
                    u16* __restrict__ cath, u16* __restrict__ catl)
{
  __shared__ int   idx_s[128];
  __shared__ float w_s[128];
  const int row = blockIdx.x, tid = threadIdx.x;
  const int kk = knp[0];
  if(tid < 128){
    idx_s[tid] = (tid < kk) ? (tidx[row*128+tid] & 8191) : 0;
    w_s[tid]   = (tid < kk) ? tw[row*128+tid] : 0.f;
  }
  __syncthreads();
  const int c = tid*4;
  float a0=0,a1=0,a2=0,a3=0;
  for(int j=0;j<kk && j<128;j++){
    const ushort4 vv = *(const ushort4*)&v[(size_t)idx_s[j]*1024 + c];
    const float w = w_s[j];
    a0 += w*bf2f(vv.x); a1 += w*bf2f(vv.y); a2 += w*bf2f(vv.z); a3 += w*bf2f(vv.w);
  }
  ushort4 oh, ol;
  split2(a0, oh.x, ol.x); split2(a1, oh.y, ol.y);
  split2(a2, oh.z, ol.z); split2(a3, oh.w, ol.w);
  ((ushort4*)(cath + (size_t)row*2048 + 1024))[tid] = oh;
  ((ushort4*)(catl + (size_t)row*2048 + 1024))[tid] = ol;
}

// bias_v[m] = dot(bq, k2[m]) / 32   (k2 = split-bf16)
__global__ __launch_bounds__(256)
void bias_v_kernel(const float* __restrict__ bq, const u16* __restrict__ k2h,
                   const u16* __restrict__ k2l, float* __restrict__ out)
{
  __shared__ float buf[4];
  const int row = blockIdx.x, tid = threadIdx.x;
  const ushort4 h4 = ((const ushort4*)(k2h + (size_t)row*1024))[tid];
  const ushort4 l4 = ((const ushort4*)(k2l + (size_t)row*1024))[tid];
  const float4 b4 = ((const float4*)bq)[tid];
  float s = b4.x*(bf2f(h4.x)+bf2f(l4.x)) + b4.y*(bf2f(h4.y)+bf2f(l4.y))
          + b4.z*(bf2f(h4.z)+bf2f(l4.z)) + b4.w*(bf2f(h4.w)+bf2f(l4.w));
  s = bredsum(s, buf, tid);
  if(tid==0) out[row] = s * 0.03125f;
}

// ============================================================================
// H: softmax over 512 + top-k_e mask, one WAVE per row (4 rows/block).
// ============================================================================
__global__ __launch_bounds__(256)
void softmax_topk_h_wave(const float* __restrict__ dv, const int* __restrict__ kep,
                         float* __restrict__ H)
{
  const int wave = threadIdx.x >> 6, lane = threadIdx.x & 63;
  const int row = blockIdx.x*4 + wave;
  const float* x = dv + (size_t)row*512 + lane*8;
  const float4 a = *(const float4*)x;
  const float4 b = *(const float4*)(x+4);
  float vals[8] = {a.x,a.y,a.z,a.w,b.x,b.y,b.z,b.w};

  float mx = vals[0];
  #pragma unroll
  for(int j=1;j<8;j++) mx = fmaxf(mx, vals[j]);
  #pragma unroll
  for(int o=32;o;o>>=1) mx = fmaxf(mx, __shfl_xor(mx, o));
  float e[8], se = 0.f;
  #pragma unroll
  for(int j=0;j<8;j++){ e[j] = expf(vals[j]-mx); se += e[j]; }
  #pragma unroll
  for(int o=32;o;o>>=1) se += __shfl_xor(se, o);
  const float inv = 1.f/se;

  const int k = kep[0];
  unsigned int selmask = 0;
  for(int r=0;r<k;r++){
    unsigned long long best = 0;
    #pragma unroll
    for(int j=0;j<8;j++){
      if(!((selmask>>j)&1u)){
        const unsigned long long key =
          ((unsigned long long)fmap(vals[j]) << 9) | (unsigned long long)(511 - (lane*8+j));
        if(key > best) best = key;
      }
    }
    #pragma unroll
    for(int o=32;o;o>>=1){
      const unsigned long long other = __shfl_xor(best, o);
      if(other > best) best = other;
    }
    const int bidx = 511 - (int)(best & 511ull);
    if((bidx>>3) == lane) selmask |= 1u << (bidx & 7);
  }

  float4 o0, o1;
  o0.x = (selmask&  1u) ? e[0]*inv : 0.f;
  o0.y = (selmask&  2u) ? e[1]*inv : 0.f;
  o0.z = (selmask&  4u) ? e[2]*inv : 0.f;
  o0.w = (selmask&  8u) ? e[3]*inv : 0.f;
  o1.x = (selmask& 16u) ? e[4]*inv : 0.f;
  o1.y = (selmask& 32u) ? e[5]*inv : 0.f;
  o1.z = (selmask& 64u) ? e[6]*inv : 0.f;
  o1.w = (selmask&128u) ? e[7]*inv : 0.f;
  float* outp = H + (size_t)row*512 + lane*8;
  *(float4*)outp     = o0;
  *(float4*)(outp+4) = o1;
}

// ============================================================================
extern "C" void kernel_launch(void* const* d_in, const int* in_sizes, int n_in,
                              void* d_out, int out_size, void* d_ws, size_t ws_size,
                              hipStream_t stream)
{
  const float* inputs = (const float*)d_in[0];
  const float* noise  = (const float*)d_in[1];
  const float* emu    = (const float*)d_in[2];
  const float* elsig  = (const float*)d_in[3];
  const float* Wq = (const float*)d_in[4];  const float* bq = (const float*)d_in[5];
  const float* Wk = (const float*)d_in[6];  const float* bk = (const float*)d_in[7];
  const float* Wv = (const float*)d_in[8];  const float* bv = (const float*)d_in[9];
  const float* W1 = (const float*)d_in[10]; const float* b1 = (const float*)d_in[11];
  const float* W2 = (const float*)d_in[12]; const float* b2 = (const float*)d_in[13];
  const float* g_in = (const float*)d_in[14]; const float* b_in = (const float*)d_in[15];
  const float* g_e  = (const float*)d_in[16]; const float* b_e  = (const float*)d_in[17];
  const int* knp = (const int*)d_in[18];
  const int* kep = (const int*)d_in[19];

  float* out = (float*)d_out;
  float* out_edges = out;                             // 512*1024
  float* out_H     = out + 512*1024;                  // 8192*512
  float* out_dots  = out + 512*1024 + 8192*512;       // 512*8192

  // ---- workspace (~112 MB peak, stream-ordered reuse) ----
  char* p = (char*)d_ws;
  const size_t MB = 1024ull*1024;
  u16* xh = (u16*)(p + 0*MB);            // x split, live to the end (dots_v)
  u16* xl = (u16*)(p + 16*MB);
  u16* kb = (u16*)(p + 32*MB);           // k bf16, dead after dots GEMM
  u16* vb = (u16*)(p + 48*MB);           // v bf16, dead after gather
  float* dotsvf = (float*)(p + 32*MB);   // dots_v fp32 (reuses kb region)
  // weights [64,88)
  u16* WkTh = (u16*)(p + 64*MB);  u16* WkTl = (u16*)(p + 66*MB);
  u16* WvTh = (u16*)(p + 68*MB);
  u16* WqTh = (u16*)(p + 70*MB);
  u16* Wqh  = (u16*)(p + 72*MB);  u16* Wql  = (u16*)(p + 74*MB);   // raw (no T)
  u16* W1Th = (u16*)(p + 76*MB);  u16* W1Tl = (u16*)(p + 80*MB);
  u16* W2Th = (u16*)(p + 84*MB);  u16* W2Tl = (u16*)(p + 86*MB);
  // small [88,102)
  u16* cath = (u16*)(p + 88*MB);  u16* catl = (u16*)(p + 90*MB);
  u16* qmb  = (u16*)(p + 92*MB);
  u16* h1h  = (u16*)(p + 93*MB);  u16* h1l  = (u16*)(p + 94*MB);
  u16* eoh  = (u16*)(p + 95*MB);  u16* eol  = (u16*)(p + 96*MB);
  u16* k2h  = (u16*)(p + 97*MB);  u16* k2l  = (u16*)(p + 98*MB);
  u16* Gth  = (u16*)(p + 99*MB);  u16* Gtl  = (u16*)(p + 100*MB);
  int*   tidx  = (int*)  (p + 101*MB);
  float* tw    = (float*)(p + 101*MB + 256*1024);
  float* biasv = (float*)(p + 101*MB + 512*1024);
  float* part  = (float*)(p + 104*MB);   // split-K partials: 4*512*1024*4 = 8MB

  hipMemsetAsync(tidx, 0, 512ull*128*4, stream);
  hipMemsetAsync(tw,   0, 512ull*128*4, stream);

  // weight prep
  transpose_split<<<dim3(32,32),256,0,stream>>>(Wk, WkTh, WkTl, 1024, 1024);
  transpose_split<<<dim3(32,64),256,0,stream>>>(W1, W1Th, W1Tl, 2048, 1024);
  transpose_split<<<dim3(32,32),256,0,stream>>>(W2, W2Th, W2Tl, 1024, 1024);
  transpose_plain<<<dim3(32,32),256,0,stream>>>(Wv, WvTh, 1024, 1024);
  transpose_plain<<<dim3(32,32),256,0,stream>>>(Wq, WqTh, 1024, 1024);
  split_convert<<<1024,256,0,stream>>>(Wq, Wqh, Wql);

  layernorm_rows<<<8192,256,0,stream>>>(inputs, g_in, b_in, xh, xl, 1024);
  edges_ln<<<512,256,0,stream>>>(noise, emu, elsig, g_e, b_e, cath, catl, 2048);

  const size_t MN = 512ull*1024;
  // --- dots chain (plain bf16; selection-tolerant) ---
  // k = relu(x@Wk+bk): M=8192 -> 64-tile, grid (8,128)
  gemm1_64<true,1><<<dim3(8,128),256,0,stream>>>(xh,1024, WkTh,1024, bk, 1.f,
                                                 kb,nullptr, nullptr, 1024,1024,8192);
  gemm1_64<true,1><<<dim3(8,128),256,0,stream>>>(xh,1024, WvTh,1024, bv, 1.f,
                                                 vb,nullptr, nullptr, 1024,1024,8192);
  // qm = relu(cat@Wq+bq): M=512 -> split-K4, grid (8,8,4)
  gemm1_64<false,4><<<dim3(8,8,4),256,0,stream>>>(cath,2048, WqTh,1024, nullptr, 1.f,
                                                  nullptr,nullptr, part, 1024,1024,512);
  reduce_epi<true,4><<<512,256,0,stream>>>(part, bq, 1.f, nullptr,nullptr, qmb,nullptr, MN, 1024);
  // dots = qm@k^T / 32 -> fp32 d_out, grid (64,8)
  gemm1_64<false,1><<<dim3(64,8),256,0,stream>>>(qmb,1024, kb,1024, nullptr, 0.03125f,
                                                 nullptr,out_dots, nullptr, 1024,8192,512);
  softmax_topk_a<<<512,256,0,stream>>>(out_dots, knp, tidx, tw);
  gather_updates<<<512,256,0,stream>>>(tidx, tw, knp, vb, cath, catl);

  // --- edges + H chain (split-bf16, fp32-class), all M=512 -> split-K4 ---
  gemm3_64<false,4><<<dim3(8,8,4),256,0,stream>>>(cath,catl,2048, W1Th,W1Tl,2048,
                                                  nullptr,1.f, nullptr,nullptr,nullptr,
                                                  part, 2048,1024,512);
  reduce_epi<true,4><<<512,256,0,stream>>>(part, b1, 1.f, h1h,h1l, nullptr,nullptr, MN, 1024);
  gemm3_64<false,4><<<dim3(8,8,4),256,0,stream>>>(h1h,h1l,1024, W2Th,W2Tl,1024,
                                                  nullptr,1.f, nullptr,nullptr,nullptr,
                                                  part, 1024,1024,512);
  reduce_epi<false,4><<<512,256,0,stream>>>(part, b2, 1.f, eoh,eol, nullptr,out_edges, MN, 1024);
  gemm3_64<false,4><<<dim3(8,8,4),256,0,stream>>>(eoh,eol,1024, WkTh,WkTl,1024,
                                                  nullptr,1.f, nullptr,nullptr,nullptr,
                                                  part, 1024,1024,512);
  reduce_epi<true,4><<<512,256,0,stream>>>(part, bk, 1.f, k2h,k2l, nullptr,nullptr, MN, 1024);
  // Gt[m,e] = sum_d k2[m,d]*Wq[e,d]
  gemm3_64<false,4><<<dim3(8,8,4),256,0,stream>>>(k2h,k2l,1024, Wqh,Wql,1024,
                                                  nullptr,1.f, nullptr,nullptr,nullptr,
                                                  part, 1024,1024,512);
  reduce_epi<false,4><<<512,256,0,stream>>>(part, nullptr, 1.f, Gth,Gtl, nullptr,nullptr, MN, 1024);
  bias_v_kernel<<<512,256,0,stream>>>(bq, k2h, k2l, biasv);
  // dots_v = x@Gt^T / 32 + biasv : M=8192, grid (4,128)
  gemm3_64<false,1><<<dim3(4,128),256,0,stream>>>(xh,xl,1024, Gth,Gtl,1024,
                                                  biasv, 0.03125f, nullptr,nullptr,dotsvf,
                                                  nullptr, 1024,512,8192);
  softmax_topk_h_wave<<<2048,256,0,stream>>>(dotsvf, kep, out_H);
}